// Round 15
// baseline (365.758 us; speedup 1.0000x reference)
//
#include <hip/hip_runtime.h>
#include <stdint.h>

typedef unsigned short u16;
typedef unsigned int u32;
typedef __attribute__((ext_vector_type(8))) __bf16 bf16x8;
typedef __attribute__((ext_vector_type(4))) float f32x4;

#define DEVINL __device__ __forceinline__

DEVINL float bf2f(u16 u){ union{u32 i; float f;} c; c.i = ((u32)u)<<16; return c.f; }
DEVINL u16 f2bf(float f){ union{float f; u32 i;} c; c.f=f; u32 u=c.i; return (u16)((u + 0x7fffu + ((u>>16)&1u))>>16); }
DEVINL u32 pack2(float a, float b){ return (u32)f2bf(a) | ((u32)f2bf(b)<<16); }

// parity of sign(e_a * e_b) in Cl(4,1) (used only for SIG_DIAG fold: sign of e_l^2)
DEVINL int sign_neg(int a, int b){
  int s = __popc((a>>1)&b) + __popc((a>>2)&b) + __popc((a>>3)&b) + __popc((a>>4)&b) + ((a&b)>>4);
  return s & 1;
}

// ---- Cl(4,1) -> M4(C) rep: blade I -> generalized permutation matrix:
// row r has single nonzero i^ph[I][r] at column col[I][r].
struct GTab { int col[32][4]; int ph[32][4]; };
constexpr GTab make_gtab(){
  GTab g{};
  int gc[5][4] = {}; int gp[5][4] = {};
  for (int r=0;r<4;r++){
    const int a=(r>>1)&1, b=r&1;
    gc[0][r]=r^2; gp[0][r]=0;                        // e0 = s1 x I
    gc[1][r]=r^2; gp[1][r]= a?1:3;                   // e1 = s2 x I
    gc[2][r]=r^1; gp[2][r]= a?2:0;                   // e2 = s3 x s1
    gc[3][r]=r^1; gp[3][r]=((a?2:0)+(b?1:3))&3;      // e3 = s3 x s2
    gc[4][r]=r;   gp[4][r]=(3+(a?2:0)+(b?2:0))&3;    // e4 = -i s3 x s3 (e4^2=-I)
  }
  for (int I=0;I<32;I++){
    for (int r=0;r<4;r++){ g.col[I][r]=r; g.ph[I][r]=0; }
    for (int bit=0;bit<5;bit++) if ((I>>bit)&1){
      for (int r=0;r<4;r++){
        const int c = g.col[I][r];
        g.ph[I][r]  = (g.ph[I][r] + gp[bit][c]) & 3;
        g.col[I][r] = gc[bit][c];
      }
    }
  }
  return g;
}
constexpr GTab GT = make_gtab();

// mv (32 reals) -> 4x4 complex matrix
DEVINL void mv2mat(const float (&x)[32], float (&Mre)[4][4], float (&Mim)[4][4]){
  #pragma unroll
  for (int r=0;r<4;r++)
    #pragma unroll
    for (int c=0;c<4;c++){ Mre[r][c]=0.f; Mim[r][c]=0.f; }
  #pragma unroll
  for (int l=0;l<32;l++){
    #pragma unroll
    for (int r=0;r<4;r++){
      constexpr const GTab& G = GT;
      const int c = G.col[l][r], p = G.ph[l][r];
      if (p==0) Mre[r][c] += x[l];
      else if (p==1) Mim[r][c] += x[l];
      else if (p==2) Mre[r][c] -= x[l];
      else Mim[r][c] -= x[l];
    }
  }
}

// v[c][r8] (r8<4: Re M[r8][c], r8>=4: Im M[r8-4][c]) -> mv
DEVINL void mat2mv(const float (&v)[4][8], float (&x)[32]){
  #pragma unroll
  for (int l=0;l<32;l++){
    float s = 0.f;
    #pragma unroll
    for (int r=0;r<4;r++){
      constexpr const GTab& G = GT;
      const int c = G.col[l][r], p = G.ph[l][r];
      if (p==0) s += v[c][r];
      else if (p==1) s += v[c][4+r];
      else if (p==2) s -= v[c][r];
      else s -= v[c][4+r];
    }
    x[l] = 0.25f*s;
  }
}

DEVINL void gload_lds16(const void* g, void* l){
  __builtin_amdgcn_global_load_lds(
    (const __attribute__((address_space(1))) void*)g,
    (__attribute__((address_space(3))) void*)l, 16, 0, 0);
}
// non-temporal variant (CPol NT=2): stream without polluting L2
DEVINL void gload_lds16_nt(const void* g, void* l){
  __builtin_amdgcn_global_load_lds(
    (const __attribute__((address_space(1))) void*)g,
    (__attribute__((address_space(3))) void*)l, 16, 0, 2);
}

// ---------------- x -> A-matrix: Am[(bs*4+c)][i*8+kk8] bf16 ----------------------
__global__ __launch_bounds__(256) void k_v2m(const float* __restrict__ x, u16* __restrict__ Am){
  const int bs = blockIdx.x, i = threadIdx.x;
  const float* xp = x + ((size_t)bs*256 + i)*32;
  float xv[32];
  #pragma unroll
  for (int q=0;q<8;q++){
    float4 v = *(const float4*)(xp + q*4);
    xv[q*4+0]=v.x; xv[q*4+1]=v.y; xv[q*4+2]=v.z; xv[q*4+3]=v.w;
  }
  float Mre[4][4], Mim[4][4];
  mv2mat(xv, Mre, Mim);
  #pragma unroll
  for (int c=0;c<4;c++){
    u32 w0 = pack2(Mre[0][c], Mre[1][c]);
    u32 w1 = pack2(Mre[2][c], Mre[3][c]);
    u32 w2 = pack2(Mim[0][c], Mim[1][c]);
    u32 w3 = pack2(Mim[2][c], Mim[3][c]);
    *(uint4*)(Am + ((size_t)(bs*4+c))*2048 + i*8) = make_uint4(w0,w1,w2,w3);
  }
}

// ---------------- w -> B fragment-order --------------------------------------------
// Bfo[sel][kq(32)][nblk(128)][kk(2)][lane(64)][e(8)]: value B[k][(o,r8)] = W8[o,i][r8][kk8]
// where n = o*8+r8 = nblk*16 + (lane&15), k = i*8+kk8 = kq*64 + kk*32 + (lane>>4)*8 + e
__global__ __launch_bounds__(256) void k_w2m(const float* __restrict__ wq, const float* __restrict__ wk,
                                             const float* __restrict__ wv, const float* __restrict__ wo,
                                             u16* __restrict__ Bfo){
  const int bid = blockIdx.x, i = threadIdx.x;
  const int wsel = bid>>8, o = bid&255;
  const float* w = wsel==0?wq: wsel==1?wk: wsel==2?wv: wo;
  const float* wp = w + ((size_t)o*256 + i)*32;
  float wv32[32];
  #pragma unroll
  for (int q=0;q<8;q++){
    float4 v = *(const float4*)(wp + q*4);
    wv32[q*4+0]=v.x; wv32[q*4+1]=v.y; wv32[q*4+2]=v.z; wv32[q*4+3]=v.w;
  }
  float Wre[4][4], Wim[4][4];
  mv2mat(wv32, Wre, Wim);
  u16* base = Bfo + (size_t)wsel*4194304 + (size_t)(i>>3)*131072 + (o>>1)*1024
            + ((i>>2)&1)*512;
  const int lanebase = (o&1)*8 + (i&3)*16;
  #pragma unroll
  for (int r8=0;r8<8;r8++){
    float e0,e1,e2,e3,e4,e5,e6,e7;
    if (r8<4){
      e0=Wre[r8][0]; e1=Wre[r8][1]; e2=Wre[r8][2]; e3=Wre[r8][3];
      e4=-Wim[r8][0]; e5=-Wim[r8][1]; e6=-Wim[r8][2]; e7=-Wim[r8][3];
    } else {
      e0=Wim[r8-4][0]; e1=Wim[r8-4][1]; e2=Wim[r8-4][2]; e3=Wim[r8-4][3];
      e4=Wre[r8-4][0]; e5=Wre[r8-4][1]; e6=Wre[r8-4][2]; e7=Wre[r8-4][3];
    }
    *(uint4*)(base + (lanebase + r8)*8) =
      make_uint4(pack2(e0,e1), pack2(e2,e3), pack2(e4,e5), pack2(e6,e7));
  }
}

// ---- one k-phase of the matrix-basis GEMM ----------------------------------------
// Consumes B0 (kk0 frags, prefetched last phase) + B1 (loaded at top);
// prefetches B0n = kk0 frags of kq+1 under this phase's MFMA cluster.
DEVINL void mg_phase(int kq, int cbuf, const u16* __restrict__ Wsel, const int (&boff)[4][2],
                     const u16* __restrict__ Am, int row0, int sbase, int lane,
                     u16* SM, uint4 (&B0)[4], uint4 (&B0n)[4],
                     f32x4 (&acc)[4][4], int wm, int wn, int lo, int hi){
  const u16* Wq = Wsel + (size_t)kq*131072;
  uint4 B1[4];
  #pragma unroll
  for (int fn=0; fn<4; ++fn) B1[fn] = *(const uint4*)(Wq + boff[fn][1]);
  // outstanding: A(kq)4 (oldest) + B0(kq)4 + B1(kq)4 = 12 -> retire A(kq)
  asm volatile("s_waitcnt vmcnt(8)" ::: "memory");
  __builtin_amdgcn_sched_barrier(0);
  __builtin_amdgcn_s_barrier();                // all waves' A(kq) landed; buf^1 free
  __builtin_amdgcn_sched_barrier(0);
  if (kq+1 < 32){                              // stage A(kq+1), non-temporal
    #pragma unroll
    for (int cc=0;cc<4;cc++){
      const int base = sbase + cc*64;
      const int idx = base + lane;
      const int rr = idx>>3, g = idx&7;
      gload_lds16_nt(Am + (size_t)(row0+rr)*2048 + (kq+1)*64 + ((g^(rr&7))*8),
                     SM + (cbuf^1)*8192 + base*8);
    }
  }
  const u16* Ab = SM + cbuf*8192;
  bf16x8 af0[4];
  #pragma unroll
  for (int f=0;f<4;f++){
    const int ra = wm*64 + f*16 + lo;
    af0[f] = *(const bf16x8*)(Ab + ra*64 + ((hi ^ (ra&7))*8));
  }
  if (kq+1 < 32){                              // prefetch next kk0 frags (full-phase cover)
    const u16* Wn = Wq + 131072;
    #pragma unroll
    for (int fn=0; fn<4; ++fn) B0n[fn] = *(const uint4*)(Wn + boff[fn][0]);
  }
  __builtin_amdgcn_s_setprio(1);
  #pragma unroll
  for (int fm=0;fm<4;fm++){
    #pragma unroll
    for (int fn=0;fn<4;fn++)
      acc[fm][fn] = __builtin_amdgcn_mfma_f32_16x16x32_bf16(
          af0[fm], *(const bf16x8*)&B0[fn], acc[fm][fn], 0,0,0);
  }
  __builtin_amdgcn_s_setprio(0);
  bf16x8 af1[4];
  #pragma unroll
  for (int f=0;f<4;f++){
    const int ra = wm*64 + f*16 + lo;
    af1[f] = *(const bf16x8*)(Ab + ra*64 + (((4+hi) ^ (ra&7))*8));
  }
  __builtin_amdgcn_s_setprio(1);
  #pragma unroll
  for (int fm=0;fm<4;fm++){
    #pragma unroll
    for (int fn=0;fn<4;fn++)
      acc[fm][fn] = __builtin_amdgcn_mfma_f32_16x16x32_bf16(
          af1[fm], *(const bf16x8*)&B1[fn], acc[fm][fn], 0,0,0);
  }
  __builtin_amdgcn_s_setprio(0);
}

// ---------------- matrix-basis GEMM: C = Am x Bfo, fused m2v epilogue --------------
// M=4096 (bs,c), K=2048 (i,kk8), N = 6144 (qkv) or 2048 (wo). 128x128 tile, 4 waves.
// A double-buffered LDS (NT stages); B reg-streamed with half prefetch; 1 barrier/phase.
template<int EPI>
__global__ __launch_bounds__(256) void k_mgemm(const u16* __restrict__ Am, const u16* __restrict__ Bfo,
                                               u16* __restrict__ qkv, float* __restrict__ dout,
                                               float* __restrict__ Nqp, float* __restrict__ Nkp){
  constexpr int NT = (EPI==0)?48:16;
  constexpr int NWG = 32*NT;
  __shared__ __align__(16) u16 SM[128*136];      // loop: A buf0 [0,8192), buf1 [8192,16384)
  const int wg = blockIdx.x;
  const int bid = (wg&7)*(NWG/8) + (wg>>3);      // bijective XCD chunking
  const int tn = bid>>5, tm = bid&31;            // tn-major: B panel per XCD
  const int row0 = tm*128, col0 = tn*128;
  const int sel   = (EPI==0)? (col0>>11) : 3;
  const int ncol0 = (EPI==0)? (col0&2047) : col0;
  const u16* Wsel = Bfo + (size_t)sel*4194304;
  const int t = threadIdx.x, lane = t&63, wid = t>>6;
  const int wm = wid>>1, wn = wid&1, lo = lane&15, hi = lane>>4;

  int boff[4][2];
  #pragma unroll
  for (int fn=0; fn<4; ++fn){
    const int nblk = (ncol0>>4) + wn*4 + fn;
    #pragma unroll
    for (int kk=0; kk<2; ++kk)
      boff[fn][kk] = (nblk*2+kk)*512 + lane*8;
  }

  f32x4 acc[4][4];
  #pragma unroll
  for(int a=0;a<4;a++){
    #pragma unroll
    for(int b=0;b<4;b++){ acc[a][b] = (f32x4){0.f,0.f,0.f,0.f}; }
  }

  const int sbase = (wid*4)*64;
  // prologue: stage A(0) into buf0 (NT), prefetch B0 of kq0
  #pragma unroll
  for (int cc=0;cc<4;cc++){
    const int base = sbase + cc*64;
    const int idx = base + lane;
    const int rr = idx>>3, g = idx&7;
    gload_lds16_nt(Am + (size_t)(row0+rr)*2048 + ((g^(rr&7))*8), SM + base*8);
  }
  uint4 B0a[4], B0b[4];
  #pragma unroll
  for (int fn=0; fn<4; ++fn) B0a[fn] = *(const uint4*)(Wsel + boff[fn][0]);

  #pragma unroll 1
  for (int kq2=0; kq2<16; ++kq2){
    mg_phase(2*kq2,   0, Wsel, boff, Am, row0, sbase, lane, SM, B0a, B0b, acc, wm, wn, lo, hi);
    mg_phase(2*kq2+1, 1, Wsel, boff, Am, row0, sbase, lane, SM, B0b, B0a, acc, wm, wn, lo, hi);
  }

  // ---- epilogue: dump C tile to LDS, reassemble multivectors, m2v + normalize ----
  __syncthreads();
  #pragma unroll
  for (int fm=0;fm<4;fm++){
    #pragma unroll
    for (int r=0;r<4;r++){
      const int mL = wm*64 + fm*16 + hi*4 + r;
      #pragma unroll
      for (int fn=0;fn<4;fn++){
        const int nL = wn*64 + fn*16 + lo;
        SM[mL*136 + nL] = f2bf(acc[fm][fn][r]);
      }
    }
  }
  __syncthreads();
  const int bsL = t>>3, oLp = t&7;
  const int bs = (row0>>2) + bsL;
  const int o0w = ncol0>>3;
  float nsum = 0.f;
  #pragma unroll
  for (int u=0;u<2;u++){
    const int oL = oLp + u*8;
    float v[4][8];
    #pragma unroll
    for (int c=0;c<4;c++){
      uint4 q4 = *(const uint4*)(SM + (bsL*4+c)*136 + oL*8);
      v[c][0]=bf2f((u16)(q4.x&0xffffu)); v[c][1]=bf2f((u16)(q4.x>>16));
      v[c][2]=bf2f((u16)(q4.y&0xffffu)); v[c][3]=bf2f((u16)(q4.y>>16));
      v[c][4]=bf2f((u16)(q4.z&0xffffu)); v[c][5]=bf2f((u16)(q4.z>>16));
      v[c][6]=bf2f((u16)(q4.w&0xffffu)); v[c][7]=bf2f((u16)(q4.w>>16));
    }
    float xs[32];
    mat2mv(v, xs);
    float s = 0.f;
    #pragma unroll
    for (int l=0;l<32;l++) s += xs[l]*xs[l];
    const float rs = rsqrtf(s + 1e-6f);
    if constexpr (EPI==0){
      nsum += s/(s+1e-6f);
      if (sel == 0){
        #pragma unroll
        for (int l=0;l<32;l++) xs[l] = sign_neg(l,l)? -xs[l]*rs : xs[l]*rs;
      } else {
        #pragma unroll
        for (int l=0;l<32;l++) xs[l] *= rs;
      }
      u16* dst = qkv + ((size_t)bs*768 + sel*256 + o0w + oL)*32;
      #pragma unroll
      for (int q=0;q<4;q++)
        *(uint4*)(dst + q*8) = make_uint4(pack2(xs[q*8+0],xs[q*8+1]), pack2(xs[q*8+2],xs[q*8+3]),
                                          pack2(xs[q*8+4],xs[q*8+5]), pack2(xs[q*8+6],xs[q*8+7]));
    } else {
      float* dst = dout + ((size_t)bs*256 + o0w + oL)*32;
      #pragma unroll
      for (int q=0;q<8;q++)
        *(float4*)(dst + q*4) = make_float4(xs[q*4+0]*rs, xs[q*4+1]*rs, xs[q*4+2]*rs, xs[q*4+3]*rs);
    }
  }
  if constexpr (EPI==0){
    if (sel < 2){
      nsum += __shfl_xor(nsum,1); nsum += __shfl_xor(nsum,2); nsum += __shfl_xor(nsum,4);
      if ((t&7)==0){
        const int half = (o0w>>4)&1, h = o0w>>5;
        const int b = bs>>9, s_ = bs&511;
        float* nd = (sel==0)? Nqp : Nkp;
        nd[half*8192 + (b*8+h)*512 + s_] = nsum;
      }
    }
  }
}

// ---------------- shared 128x128 MFMA tile engine (linear-row operands) -----------
DEVINL void mm_steps(const u16* Abase, int Astride, const u16* Bbase, int Bstride, int ksteps,
                     u16* Al, u16* Bl, f32x4 (&acc)[4][4], int lane, int wid){
  const int wm = wid>>1, wn = wid&1, lo = lane&15, hi = lane>>4;
  for (int s=0; s<ksteps; ++s){
    const int k0 = s*64;
    #pragma unroll
    for (int c=0;c<4;c++){
      const int gb = (wid*4+c)*64;
      const int idx = gb + lane;
      const int r = idx>>3, j = idx&7;
      const int sw = ((j^(r&7))*8);
      gload_lds16(Abase + (size_t)r*Astride + k0 + sw, Al + gb*8);
      gload_lds16(Bbase + (size_t)r*Bstride + k0 + sw, Bl + gb*8);
    }
    __syncthreads();
    #pragma unroll
    for (int kk=0; kk<2; ++kk){
      bf16x8 af[4], bfr[4];
      #pragma unroll
      for (int f=0;f<4;f++){
        const int ra = wm*64 + f*16 + lo;
        const int jc = kk*4 + hi;
        af[f] = *(const bf16x8*)(Al + ra*64 + ((jc^(ra&7))*8));
        const int rb = wn*64 + f*16 + lo;
        bfr[f] = *(const bf16x8*)(Bl + rb*64 + ((jc^(rb&7))*8));
      }
      #pragma unroll
      for (int fm=0;fm<4;fm++){
        #pragma unroll
        for (int fn=0;fn<4;fn++)
          acc[fm][fn] = __builtin_amdgcn_mfma_f32_16x16x32_bf16(af[fm], bfr[fn], acc[fm][fn], 0,0,0);
      }
    }
    __syncthreads();
  }
}

// ---------------- score: ss + gamma*bivector, write S1 f32 and S1T bf16 -----------
__global__ __launch_bounds__(256) void k_score(const u16* __restrict__ qkv, const float* __restrict__ Nqp,
                                               const float* __restrict__ Nkp, const float* __restrict__ gptr,
                                               float* __restrict__ S1, u16* __restrict__ S1T){
  __shared__ __align__(16) u16 Al[128*64];
  __shared__ __align__(16) u16 Bl[128*64];
  __shared__ __align__(16) u16 Tl[128*136];
  const int wg = blockIdx.x;
  const int bid = (wg&7)*32 + (wg>>3);
  const int bh = bid>>4, ti=(bid>>2)&3, tj=bid&3;
  const int b = bh>>3, h = bh&7;
  const int i0=ti*128, j0=tj*128;
  const int t=threadIdx.x, lane=t&63, wid=t>>6;
  const int wm=wid>>1, wn=wid&1, lo=lane&15, hi=lane>>4;
  f32x4 acc[4][4];
  #pragma unroll
  for(int a=0;a<4;a++){
    #pragma unroll
    for(int c=0;c<4;c++){ acc[a][c] = (f32x4){0.f,0.f,0.f,0.f}; }
  }
  const u16* Abase = qkv + ((size_t)(b*512+i0))*24576 + h*1024;
  const u16* Bbase = qkv + ((size_t)(b*512+j0))*24576 + 8192 + h*1024;
  mm_steps(Abase, 24576, Bbase, 24576, 16, Al, Bl, acc, lane, wid);
  const float gamma = *gptr;
  const float rhd = 0.17677669529663687f; // 1/sqrt(32)
  float nkv[4];
  #pragma unroll
  for (int fn=0;fn<4;fn++){
    const int idx = bh*512 + j0 + wn*64 + fn*16 + lo;
    nkv[fn] = Nkp[idx] + Nkp[8192 + idx];
  }
  #pragma unroll
  for (int fm=0;fm<4;fm++){
    #pragma unroll
    for (int r=0;r<4;r++){
      const int iL = wm*64 + fm*16 + hi*4 + r;
      const int qidx = bh*512 + i0 + iL;
      const float nq = Nqp[qidx] + Nqp[8192 + qidx];
      #pragma unroll
      for (int fn=0;fn<4;fn++){
        const int jL = wn*64 + fn*16 + lo;
        const float ss = acc[fm][fn][r];
        const float biv = sqrtf(fmaxf(nq*nkv[fn] - ss*ss, 0.f) + 1e-6f);
        const float sc = (ss + gamma*biv)*rhd;
        S1[((size_t)bh*512 + i0 + iL)*512 + j0 + jL] = sc;
        Tl[jL*136 + iL] = f2bf(sc);
      }
    }
  }
  __syncthreads();
  const int jj = t>>1, half = t&1;
  u16* dst = S1T + ((size_t)bh*512 + (j0+jj))*512 + i0 + half*64;
  #pragma unroll
  for (int q=0;q<8;q++)
    *(uint4*)(dst + q*8) = *(const uint4*)(Tl + jj*136 + half*64 + q*8);
}

// ---------------- row softmax, wave-per-row (optionally masked) -------------------
__global__ __launch_bounds__(256) void k_softmax(const float* __restrict__ S, const int* __restrict__ mask,
                                                 u16* __restrict__ P, int masked){
  const int t = threadIdx.x, lane = t&63, wid = t>>6;
  const int row = blockIdx.x*4 + wid;   // bh*512 + i
  const int b = row>>12;
  const float* sp = S + (size_t)row*512;
  float4 a = *(const float4*)(sp + lane*4);
  float4 c = *(const float4*)(sp + 256 + lane*4);
  if (masked){
    const int* mp = mask + b*512;
    int4 ma = *(const int4*)(mp + lane*4);
    int4 mc = *(const int4*)(mp + 256 + lane*4);
    if (ma.x==0) a.x=-1e9f; if (ma.y==0) a.y=-1e9f; if (ma.z==0) a.z=-1e9f; if (ma.w==0) a.w=-1e9f;
    if (mc.x==0) c.x=-1e9f; if (mc.y==0) c.y=-1e9f; if (mc.z==0) c.z=-1e9f; if (mc.w==0) c.w=-1e9f;
  }
  float mx = fmaxf(fmaxf(fmaxf(a.x,a.y),fmaxf(a.z,a.w)), fmaxf(fmaxf(c.x,c.y),fmaxf(c.z,c.w)));
  #pragma unroll
  for (int o=1;o<64;o<<=1) mx = fmaxf(mx, __shfl_xor(mx,o));
  const float e0=__expf(a.x-mx), e1=__expf(a.y-mx), e2=__expf(a.z-mx), e3=__expf(a.w-mx);
  const float e4=__expf(c.x-mx), e5=__expf(c.y-mx), e6=__expf(c.z-mx), e7=__expf(c.w-mx);
  float sm = (e0+e1)+(e2+e3)+(e4+e5)+(e6+e7);
  #pragma unroll
  for (int o=1;o<64;o<<=1) sm += __shfl_xor(sm,o);
  const float inv = 1.f/sm;
  u16* pp = P + (size_t)row*512;
  *(uint2*)(pp + lane*4)       = make_uint2(pack2(e0*inv,e1*inv), pack2(e2*inv,e3*inv));
  *(uint2*)(pp + 256 + lane*4) = make_uint2(pack2(e4*inv,e5*inv), pack2(e6*inv,e7*inv));
}

// ---------------- triangle update: S1 += 0.1 * P1 @ S1b (in place, f32) ----------
__global__ __launch_bounds__(256) void k_tri(const u16* __restrict__ P1, const u16* __restrict__ S1T,
                                             float* __restrict__ S1){
  __shared__ __align__(16) u16 Al[128*64];
  __shared__ __align__(16) u16 Bl[128*64];
  const int wg = blockIdx.x;
  const int bid = (wg&7)*32 + (wg>>3);
  const int bh = bid>>4, ti=(bid>>2)&3, tj=bid&3;
  const int i0=ti*128, j0=tj*128;
  const int t=threadIdx.x, lane=t&63, wid=t>>6;
  const int wm=wid>>1, wn=wid&1, lo=lane&15, hi=lane>>4;
  f32x4 acc[4][4];
  #pragma unroll
  for(int a=0;a<4;a++){
    #pragma unroll
    for(int c=0;c<4;c++){ acc[a][c] = (f32x4){0.f,0.f,0.f,0.f}; }
  }
  const u16* Abase = P1  + ((size_t)bh*512 + i0)*512;
  const u16* Bbase = S1T + ((size_t)bh*512 + j0)*512;
  mm_steps(Abase, 512, Bbase, 512, 8, Al, Bl, acc, lane, wid);
  #pragma unroll
  for (int fm=0;fm<4;fm++){
    #pragma unroll
    for (int r=0;r<4;r++){
      const int iL = wm*64 + fm*16 + hi*4 + r;
      #pragma unroll
      for (int fn=0;fn<4;fn++){
        const int jL = wn*64 + fn*16 + lo;
        const size_t idx = ((size_t)bh*512 + i0 + iL)*512 + j0 + jL;
        S1[idx] = S1[idx] + 0.1f*acc[fm][fn][r];
      }
    }
  }
}

// ---------------- transpose V to VT[bh][d][s] ------------------------------------
__global__ __launch_bounds__(256) void k_tr_v(const u16* __restrict__ qkv, u16* __restrict__ VT){
  __shared__ u16 tile[128*129];
  const int bid=blockIdx.x;
  const int bh = bid>>5, dch=(bid>>2)&7, sch=bid&3;
  const int b=bh>>3, h=bh&7;
  const int d0=dch*128, s0=sch*128;
  const int t=threadIdx.x;
  {
    const int r=t>>1, half=t&1;
    const u16* src = qkv + ((size_t)(b*512+s0+r))*24576 + 16384 + h*1024 + d0 + half*64;
    #pragma unroll
    for (int q=0;q<8;q++){
      uint4 v = *(const uint4*)(src + q*8);
      u16* dp = tile + r*129 + half*64 + q*8;
      dp[0]=(u16)(v.x&0xffffu); dp[1]=(u16)(v.x>>16); dp[2]=(u16)(v.y&0xffffu); dp[3]=(u16)(v.y>>16);
      dp[4]=(u16)(v.z&0xffffu); dp[5]=(u16)(v.z>>16); dp[6]=(u16)(v.w&0xffffu); dp[7]=(u16)(v.w>>16);
    }
  }
  __syncthreads();
  {
    const int rr=t>>1, half=t&1;
    u16* dst = VT + ((size_t)bh*1024 + d0+rr)*512 + s0 + half*64;
    #pragma unroll
    for (int q=0;q<4;q++){
      u32 w[8];
      #pragma unroll
      for (int e=0;e<8;e++){
        const int s = half*64 + q*16 + e*2;
        w[e] = (u32)tile[s*129+rr] | ((u32)tile[(s+1)*129+rr]<<16);
      }
      *(uint4*)(dst + q*16)     = make_uint4(w[0],w[1],w[2],w[3]);
      *(uint4*)(dst + q*16 + 8) = make_uint4(w[4],w[5],w[6],w[7]);
    }
  }
}

// ---------------- PV: out = P2 @ V, epilogue writes mat-basis Amat2 ---------------
__global__ __launch_bounds__(256) void k_pv(const u16* __restrict__ P2, const u16* __restrict__ VT,
                                            u16* __restrict__ Am2){
  __shared__ __align__(16) u16 Al[128*64];
  __shared__ __align__(16) u16 Bl[128*64];
  __shared__ __align__(16) u16 Tl[128*136];
  const int wg = blockIdx.x;
  const int bid = (wg&7)*64 + (wg>>3);
  const int bh = bid>>5, ti=(bid>>3)&3, td=bid&7;
  const int b=bh>>3, h=bh&7;
  const int i0=ti*128, d0=td*128;
  const int t=threadIdx.x, lane=t&63, wid=t>>6;
  const int wm=wid>>1, wn=wid&1, lo=lane&15, hi=lane>>4;
  f32x4 acc[4][4];
  #pragma unroll
  for(int a=0;a<4;a++){
    #pragma unroll
    for(int c=0;c<4;c++){ acc[a][c] = (f32x4){0.f,0.f,0.f,0.f}; }
  }
  const u16* Abase = P2 + ((size_t)bh*512 + i0)*512;
  const u16* Bbase = VT + ((size_t)bh*1024 + d0)*512;
  mm_steps(Abase, 512, Bbase, 512, 8, Al, Bl, acc, lane, wid);
  #pragma unroll
  for (int fm=0;fm<4;fm++){
    #pragma unroll
    for (int r=0;r<4;r++){
      const int sL = wm*64 + fm*16 + hi*4 + r;
      #pragma unroll
      for (int fn=0;fn<4;fn++){
        const int dL = wn*64 + fn*16 + lo;
        Tl[sL*136 + dL] = f2bf(acc[fm][fn][r]);
      }
    }
  }
  __syncthreads();
  // reassemble multivectors (128 s x 4 hd) and write A-matrix rows for gemm<1>
  #pragma unroll
  for (int u=0;u<2;u++){
    const int idx = t + u*256;
    const int sL = idx>>2, hdL = idx&3;
    const u16* tp = Tl + sL*136 + hdL*32;
    float xv[32];
    #pragma unroll
    for (int q=0;q<4;q++){
      uint4 v = *(const uint4*)(tp + q*8);
      xv[q*8+0]=bf2f((u16)(v.x&0xffffu)); xv[q*8+1]=bf2f((u16)(v.x>>16));
      xv[q*8+2]=bf2f((u16)(v.y&0xffffu)); xv[q*8+3]=bf2f((u16)(v.y>>16));
      xv[q*8+4]=bf2f((u16)(v.z&0xffffu)); xv[q*8+5]=bf2f((u16)(v.z>>16));
      xv[q*8+6]=bf2f((u16)(v.w&0xffffu)); xv[q*8+7]=bf2f((u16)(v.w>>16));
    }
    float Mre[4][4], Mim[4][4];
    mv2mat(xv, Mre, Mim);
    const int e = h*32 + td*4 + hdL;
    const size_t mrow = ((size_t)(b*512 + i0 + sL))*4;
    #pragma unroll
    for (int c=0;c<4;c++){
      u32 w0 = pack2(Mre[0][c], Mre[1][c]);
      u32 w1 = pack2(Mre[2][c], Mre[3][c]);
      u32 w2 = pack2(Mim[0][c], Mim[1][c]);
      u32 w3 = pack2(Mim[2][c], Mim[3][c]);
      *(uint4*)(Am2 + (mrow + c)*2048 + e*8) = make_uint4(w0,w1,w2,w3);
    }
  }
}

extern "C" void kernel_launch(void* const* d_in, const int* in_sizes, int n_in,
                              void* d_out, int out_size, void* d_ws, size_t ws_size,
                              hipStream_t stream) {
  const float* x  = (const float*)d_in[0];
  const float* wq = (const float*)d_in[1];
  const float* wk = (const float*)d_in[2];
  const float* wv = (const float*)d_in[3];
  const float* wo = (const float*)d_in[4];
  const float* gamma = (const float*)d_in[5];
  const int*   mask  = (const int*)d_in[6];
  float* out = (float*)d_out;

  char* ws = (char*)d_ws;
  size_t off = 0;
  auto alloc = [&](size_t n){ char* p = ws + off; off += (n + 255) & ~(size_t)255; return p; };
  u16*  Am  = (u16*) alloc(16777216);   // [4096][2048] bf16 (later: P1 8MB, then Am2)
  u16*  Bfo = (u16*) alloc(33554432);   // [4][32][128][2][64][8] bf16
  u16*  qkv = (u16*) alloc(50331648);   // [1024][768][32] bf16
  float* Nqp = (float*)alloc(65536);    // [2][8192]
  float* Nkp = (float*)alloc(65536);
  float* S1 = (float*)alloc(16777216);  // [16][512][512] f32 (later: VT)
  u16*  S1T = (u16*) alloc(8388608);
  u16*  P2  = (u16*) alloc(8388608);
  u16*  P1  = (u16*)Am;                 // alias: Am dead after gemm<0>
  u16*  VT  = (u16*)S1;                 // alias: S1 dead after softmax2
  u16*  Am2 = (u16*)Am;                 // alias: P1 dead after k_tri

  k_v2m<<<1024, 256, 0, stream>>>(x, Am);
  k_w2m<<<1024, 256, 0, stream>>>(wq, wk, wv, wo, Bfo);
  k_mgemm<0><<<1536, 256, 0, stream>>>(Am, Bfo, qkv, nullptr, Nqp, Nkp);
  k_score<<<256, 256, 0, stream>>>(qkv, Nqp, Nkp, gamma, S1, S1T);
  k_softmax<<<2048, 256, 0, stream>>>(S1, mask, P1, 0);
  k_tri<<<256, 256, 0, stream>>>(P1, S1T, S1);
  k_softmax<<<2048, 256, 0, stream>>>(S1, mask, P2, 1);
  k_tr_v<<<512, 256, 0, stream>>>(qkv, VT);
  k_pv<<<512, 256, 0, stream>>>(P2, VT, Am2);
  k_mgemm<1><<<512, 256, 0, stream>>>(Am2, Bfo, nullptr, out, nullptr, nullptr);
}

// Round 16
// 275.565 us; speedup vs baseline: 1.3273x; 1.3273x over previous
//
#include <hip/hip_runtime.h>
#include <stdint.h>

typedef unsigned short u16;
typedef unsigned int u32;
typedef __attribute__((ext_vector_type(8))) __bf16 bf16x8;
typedef __attribute__((ext_vector_type(4))) float f32x4;

#define DEVINL __device__ __forceinline__

DEVINL float bf2f(u16 u){ union{u32 i; float f;} c; c.i = ((u32)u)<<16; return c.f; }
DEVINL u16 f2bf(float f){ union{float f; u32 i;} c; c.f=f; u32 u=c.i; return (u16)((u + 0x7fffu + ((u>>16)&1u))>>16); }
DEVINL u32 pack2(float a, float b){ return (u32)f2bf(a) | ((u32)f2bf(b)<<16); }

// parity of sign(e_a * e_b) in Cl(4,1) (used only for SIG_DIAG fold: sign of e_l^2)
DEVINL int sign_neg(int a, int b){
  int s = __popc((a>>1)&b) + __popc((a>>2)&b) + __popc((a>>3)&b) + __popc((a>>4)&b) + ((a&b)>>4);
  return s & 1;
}

// ---- Cl(4,1) -> M4(C) rep: blade I -> generalized permutation matrix:
// row r has single nonzero i^ph[I][r] at column col[I][r].
struct GTab { int col[32][4]; int ph[32][4]; };
constexpr GTab make_gtab(){
  GTab g{};
  int gc[5][4] = {}; int gp[5][4] = {};
  for (int r=0;r<4;r++){
    const int a=(r>>1)&1, b=r&1;
    gc[0][r]=r^2; gp[0][r]=0;                        // e0 = s1 x I
    gc[1][r]=r^2; gp[1][r]= a?1:3;                   // e1 = s2 x I
    gc[2][r]=r^1; gp[2][r]= a?2:0;                   // e2 = s3 x s1
    gc[3][r]=r^1; gp[3][r]=((a?2:0)+(b?1:3))&3;      // e3 = s3 x s2
    gc[4][r]=r;   gp[4][r]=(3+(a?2:0)+(b?2:0))&3;    // e4 = -i s3 x s3 (e4^2=-I)
  }
  for (int I=0;I<32;I++){
    for (int r=0;r<4;r++){ g.col[I][r]=r; g.ph[I][r]=0; }
    for (int bit=0;bit<5;bit++) if ((I>>bit)&1){
      for (int r=0;r<4;r++){
        const int c = g.col[I][r];
        g.ph[I][r]  = (g.ph[I][r] + gp[bit][c]) & 3;
        g.col[I][r] = gc[bit][c];
      }
    }
  }
  return g;
}
constexpr GTab GT = make_gtab();

// mv (32 reals) -> 4x4 complex matrix
DEVINL void mv2mat(const float (&x)[32], float (&Mre)[4][4], float (&Mim)[4][4]){
  #pragma unroll
  for (int r=0;r<4;r++)
    #pragma unroll
    for (int c=0;c<4;c++){ Mre[r][c]=0.f; Mim[r][c]=0.f; }
  #pragma unroll
  for (int l=0;l<32;l++){
    #pragma unroll
    for (int r=0;r<4;r++){
      constexpr const GTab& G = GT;
      const int c = G.col[l][r], p = G.ph[l][r];
      if (p==0) Mre[r][c] += x[l];
      else if (p==1) Mim[r][c] += x[l];
      else if (p==2) Mre[r][c] -= x[l];
      else Mim[r][c] -= x[l];
    }
  }
}

// v[c][r8] (r8<4: Re M[r8][c], r8>=4: Im M[r8-4][c]) -> mv
DEVINL void mat2mv(const float (&v)[4][8], float (&x)[32]){
  #pragma unroll
  for (int l=0;l<32;l++){
    float s = 0.f;
    #pragma unroll
    for (int r=0;r<4;r++){
      constexpr const GTab& G = GT;
      const int c = G.col[l][r], p = G.ph[l][r];
      if (p==0) s += v[c][r];
      else if (p==1) s += v[c][4+r];
      else if (p==2) s -= v[c][r];
      else s -= v[c][4+r];
    }
    x[l] = 0.25f*s;
  }
}

DEVINL void gload_lds16(const void* g, void* l){
  __builtin_amdgcn_global_load_lds(
    (const __attribute__((address_space(1))) void*)g,
    (__attribute__((address_space(3))) void*)l, 16, 0, 0);
}

// ---------------- x -> A-matrix: Am[(bs*4+c)][i*8+kk8] bf16 ----------------------
__global__ __launch_bounds__(256) void k_v2m(const float* __restrict__ x, u16* __restrict__ Am){
  const int bs = blockIdx.x, i = threadIdx.x;
  const float* xp = x + ((size_t)bs*256 + i)*32;
  float xv[32];
  #pragma unroll
  for (int q=0;q<8;q++){
    float4 v = *(const float4*)(xp + q*4);
    xv[q*4+0]=v.x; xv[q*4+1]=v.y; xv[q*4+2]=v.z; xv[q*4+3]=v.w;
  }
  float Mre[4][4], Mim[4][4];
  mv2mat(xv, Mre, Mim);
  #pragma unroll
  for (int c=0;c<4;c++){
    u32 w0 = pack2(Mre[0][c], Mre[1][c]);
    u32 w1 = pack2(Mre[2][c], Mre[3][c]);
    u32 w2 = pack2(Mim[0][c], Mim[1][c]);
    u32 w3 = pack2(Mim[2][c], Mim[3][c]);
    *(uint4*)(Am + ((size_t)(bs*4+c))*2048 + i*8) = make_uint4(w0,w1,w2,w3);
  }
}

// ---------------- w -> B fragment-order --------------------------------------------
// Bfo[sel][kq(32)][nblk(128)][kk(2)][lane(64)][e(8)]: value B[k][(o,r8)] = W8[o,i][r8][kk8]
// where n = o*8+r8 = nblk*16 + (lane&15), k = i*8+kk8 = kq*64 + kk*32 + (lane>>4)*8 + e
__global__ __launch_bounds__(256) void k_w2m(const float* __restrict__ wq, const float* __restrict__ wk,
                                             const float* __restrict__ wv, const float* __restrict__ wo,
                                             u16* __restrict__ Bfo){
  const int bid = blockIdx.x, i = threadIdx.x;
  const int wsel = bid>>8, o = bid&255;
  const float* w = wsel==0?wq: wsel==1?wk: wsel==2?wv: wo;
  const float* wp = w + ((size_t)o*256 + i)*32;
  float wv32[32];
  #pragma unroll
  for (int q=0;q<8;q++){
    float4 v = *(const float4*)(wp + q*4);
    wv32[q*4+0]=v.x; wv32[q*4+1]=v.y; wv32[q*4+2]=v.z; wv32[q*4+3]=v.w;
  }
  float Wre[4][4], Wim[4][4];
  mv2mat(wv32, Wre, Wim);
  u16* base = Bfo + (size_t)wsel*4194304 + (size_t)(i>>3)*131072 + (o>>1)*1024
            + ((i>>2)&1)*512;
  const int lanebase = (o&1)*8 + (i&3)*16;
  #pragma unroll
  for (int r8=0;r8<8;r8++){
    float e0,e1,e2,e3,e4,e5,e6,e7;
    if (r8<4){
      e0=Wre[r8][0]; e1=Wre[r8][1]; e2=Wre[r8][2]; e3=Wre[r8][3];
      e4=-Wim[r8][0]; e5=-Wim[r8][1]; e6=-Wim[r8][2]; e7=-Wim[r8][3];
    } else {
      e0=Wim[r8-4][0]; e1=Wim[r8-4][1]; e2=Wim[r8-4][2]; e3=Wim[r8-4][3];
      e4=Wre[r8-4][0]; e5=Wre[r8-4][1]; e6=Wre[r8-4][2]; e7=Wre[r8-4][3];
    }
    *(uint4*)(base + (lanebase + r8)*8) =
      make_uint4(pack2(e0,e1), pack2(e2,e3), pack2(e4,e5), pack2(e6,e7));
  }
}

// ---- one k-phase of the matrix-basis GEMM ----------------------------------------
// Consumes B0 (kk0 frags, prefetched last phase) + B1 (loaded at top);
// prefetches B0n = kk0 frags of kq+1 under this phase's MFMA cluster.
DEVINL void mg_phase(int kq, int cbuf, const u16* __restrict__ Wsel, const int (&boff)[4][2],
                     const u16* __restrict__ Am, int row0, int sbase, int lane,
                     u16* SM, uint4 (&B0)[4], uint4 (&B0n)[4],
                     f32x4 (&acc)[4][4], int wm, int wn, int lo, int hi){
  const u16* Wq = Wsel + (size_t)kq*131072;
  uint4 B1[4];
  #pragma unroll
  for (int fn=0; fn<4; ++fn) B1[fn] = *(const uint4*)(Wq + boff[fn][1]);
  // outstanding: A(kq)4 (oldest) + B0(kq)4 + B1(kq)4 = 12 -> retire A(kq)
  asm volatile("s_waitcnt vmcnt(8)" ::: "memory");
  __builtin_amdgcn_sched_barrier(0);
  __builtin_amdgcn_s_barrier();                // all waves' A(kq) landed; buf^1 free
  __builtin_amdgcn_sched_barrier(0);
  if (kq+1 < 32){                              // stage A(kq+1)
    #pragma unroll
    for (int cc=0;cc<4;cc++){
      const int base = sbase + cc*64;
      const int idx = base + lane;
      const int rr = idx>>3, g = idx&7;
      gload_lds16(Am + (size_t)(row0+rr)*2048 + (kq+1)*64 + ((g^(rr&7))*8),
                  SM + (cbuf^1)*8192 + base*8);
    }
  }
  const u16* Ab = SM + cbuf*8192;
  bf16x8 af0[4];
  #pragma unroll
  for (int f=0;f<4;f++){
    const int ra = wm*64 + f*16 + lo;
    af0[f] = *(const bf16x8*)(Ab + ra*64 + ((hi ^ (ra&7))*8));
  }
  if (kq+1 < 32){                              // prefetch next kk0 frags (full-phase cover)
    const u16* Wn = Wq + 131072;
    #pragma unroll
    for (int fn=0; fn<4; ++fn) B0n[fn] = *(const uint4*)(Wn + boff[fn][0]);
  }
  __builtin_amdgcn_s_setprio(1);
  #pragma unroll
  for (int fm=0;fm<4;fm++){
    #pragma unroll
    for (int fn=0;fn<4;fn++)
      acc[fm][fn] = __builtin_amdgcn_mfma_f32_16x16x32_bf16(
          af0[fm], *(const bf16x8*)&B0[fn], acc[fm][fn], 0,0,0);
  }
  __builtin_amdgcn_s_setprio(0);
  bf16x8 af1[4];
  #pragma unroll
  for (int f=0;f<4;f++){
    const int ra = wm*64 + f*16 + lo;
    af1[f] = *(const bf16x8*)(Ab + ra*64 + (((4+hi) ^ (ra&7))*8));
  }
  __builtin_amdgcn_s_setprio(1);
  #pragma unroll
  for (int fm=0;fm<4;fm++){
    #pragma unroll
    for (int fn=0;fn<4;fn++)
      acc[fm][fn] = __builtin_amdgcn_mfma_f32_16x16x32_bf16(
          af1[fm], *(const bf16x8*)&B1[fn], acc[fm][fn], 0,0,0);
  }
  __builtin_amdgcn_s_setprio(0);
}

// ---------------- matrix-basis GEMM: C = Am x Bfo, fused m2v epilogue --------------
// M=4096 (bs,c), K=2048 (i,kk8), N = 6144 (qkv) or 2048 (wo). 128x128 tile, 4 waves.
// A double-buffered LDS; B reg-streamed with half prefetch; 1 barrier/phase.
template<int EPI>
__global__ __launch_bounds__(256) void k_mgemm(const u16* __restrict__ Am, const u16* __restrict__ Bfo,
                                               u16* __restrict__ qkv, float* __restrict__ dout,
                                               float* __restrict__ Nqp, float* __restrict__ Nkp){
  constexpr int NT = (EPI==0)?48:16;
  constexpr int NWG = 32*NT;
  __shared__ __align__(16) u16 SM[128*136];      // loop: A buf0 [0,8192), buf1 [8192,16384)
  const int wg = blockIdx.x;
  const int bid = (wg&7)*(NWG/8) + (wg>>3);      // bijective XCD chunking
  const int tn = bid>>5, tm = bid&31;            // tn-major: B panel per XCD
  const int row0 = tm*128, col0 = tn*128;
  const int sel   = (EPI==0)? (col0>>11) : 3;
  const int ncol0 = (EPI==0)? (col0&2047) : col0;
  const u16* Wsel = Bfo + (size_t)sel*4194304;
  const int t = threadIdx.x, lane = t&63, wid = t>>6;
  const int wm = wid>>1, wn = wid&1, lo = lane&15, hi = lane>>4;

  int boff[4][2];
  #pragma unroll
  for (int fn=0; fn<4; ++fn){
    const int nblk = (ncol0>>4) + wn*4 + fn;
    #pragma unroll
    for (int kk=0; kk<2; ++kk)
      boff[fn][kk] = (nblk*2+kk)*512 + lane*8;
  }

  f32x4 acc[4][4];
  #pragma unroll
  for(int a=0;a<4;a++){
    #pragma unroll
    for(int b=0;b<4;b++){ acc[a][b] = (f32x4){0.f,0.f,0.f,0.f}; }
  }

  const int sbase = (wid*4)*64;
  // prologue: stage A(0) into buf0, prefetch B0 of kq0
  #pragma unroll
  for (int cc=0;cc<4;cc++){
    const int base = sbase + cc*64;
    const int idx = base + lane;
    const int rr = idx>>3, g = idx&7;
    gload_lds16(Am + (size_t)(row0+rr)*2048 + ((g^(rr&7))*8), SM + base*8);
  }
  uint4 B0a[4], B0b[4];
  #pragma unroll
  for (int fn=0; fn<4; ++fn) B0a[fn] = *(const uint4*)(Wsel + boff[fn][0]);

  #pragma unroll 1
  for (int kq2=0; kq2<16; ++kq2){
    mg_phase(2*kq2,   0, Wsel, boff, Am, row0, sbase, lane, SM, B0a, B0b, acc, wm, wn, lo, hi);
    mg_phase(2*kq2+1, 1, Wsel, boff, Am, row0, sbase, lane, SM, B0b, B0a, acc, wm, wn, lo, hi);
  }

  // ---- epilogue: dump C tile to LDS, reassemble multivectors, m2v + normalize ----
  __syncthreads();
  #pragma unroll
  for (int fm=0;fm<4;fm++){
    #pragma unroll
    for (int r=0;r<4;r++){
      const int mL = wm*64 + fm*16 + hi*4 + r;
      #pragma unroll
      for (int fn=0;fn<4;fn++){
        const int nL = wn*64 + fn*16 + lo;
        SM[mL*136 + nL] = f2bf(acc[fm][fn][r]);
      }
    }
  }
  __syncthreads();
  const int bsL = t>>3, oLp = t&7;
  const int bs = (row0>>2) + bsL;
  const int o0w = ncol0>>3;
  float nsum = 0.f;
  #pragma unroll
  for (int u=0;u<2;u++){
    const int oL = oLp + u*8;
    float v[4][8];
    #pragma unroll
    for (int c=0;c<4;c++){
      uint4 q4 = *(const uint4*)(SM + (bsL*4+c)*136 + oL*8);
      v[c][0]=bf2f((u16)(q4.x&0xffffu)); v[c][1]=bf2f((u16)(q4.x>>16));
      v[c][2]=bf2f((u16)(q4.y&0xffffu)); v[c][3]=bf2f((u16)(q4.y>>16));
      v[c][4]=bf2f((u16)(q4.z&0xffffu)); v[c][5]=bf2f((u16)(q4.z>>16));
      v[c][6]=bf2f((u16)(q4.w&0xffffu)); v[c][7]=bf2f((u16)(q4.w>>16));
    }
    float xs[32];
    mat2mv(v, xs);
    float s = 0.f;
    #pragma unroll
    for (int l=0;l<32;l++) s += xs[l]*xs[l];
    const float rs = rsqrtf(s + 1e-6f);
    if constexpr (EPI==0){
      nsum += s/(s+1e-6f);
      if (sel == 0){
        #pragma unroll
        for (int l=0;l<32;l++) xs[l] = sign_neg(l,l)? -xs[l]*rs : xs[l]*rs;
      } else {
        #pragma unroll
        for (int l=0;l<32;l++) xs[l] *= rs;
      }
      u16* dst = qkv + ((size_t)bs*768 + sel*256 + o0w + oL)*32;
      #pragma unroll
      for (int q=0;q<4;q++)
        *(uint4*)(dst + q*8) = make_uint4(pack2(xs[q*8+0],xs[q*8+1]), pack2(xs[q*8+2],xs[q*8+3]),
                                          pack2(xs[q*8+4],xs[q*8+5]), pack2(xs[q*8+6],xs[q*8+7]));
    } else {
      float* dst = dout + ((size_t)bs*256 + o0w + oL)*32;
      #pragma unroll
      for (int q=0;q<8;q++)
        *(float4*)(dst + q*4) = make_float4(xs[q*4+0]*rs, xs[q*4+1]*rs, xs[q*4+2]*rs, xs[q*4+3]*rs);
    }
  }
  if constexpr (EPI==0){
    if (sel < 2){
      nsum += __shfl_xor(nsum,1); nsum += __shfl_xor(nsum,2); nsum += __shfl_xor(nsum,4);
      if ((t&7)==0){
        const int half = (o0w>>4)&1, h = o0w>>5;
        const int b = bs>>9, s_ = bs&511;
        float* nd = (sel==0)? Nqp : Nkp;
        nd[half*8192 + (b*8+h)*512 + s_] = nsum;
      }
    }
  }
}

// ---------------- shared 128x128 MFMA tile engine (linear-row operands) -----------
DEVINL void mm_steps(const u16* Abase, int Astride, const u16* Bbase, int Bstride, int ksteps,
                     u16* Al, u16* Bl, f32x4 (&acc)[4][4], int lane, int wid){
  const int wm = wid>>1, wn = wid&1, lo = lane&15, hi = lane>>4;
  for (int s=0; s<ksteps; ++s){
    const int k0 = s*64;
    #pragma unroll
    for (int c=0;c<4;c++){
      const int gb = (wid*4+c)*64;
      const int idx = gb + lane;
      const int r = idx>>3, j = idx&7;
      const int sw = ((j^(r&7))*8);
      gload_lds16(Abase + (size_t)r*Astride + k0 + sw, Al + gb*8);
      gload_lds16(Bbase + (size_t)r*Bstride + k0 + sw, Bl + gb*8);
    }
    __syncthreads();
    #pragma unroll
    for (int kk=0; kk<2; ++kk){
      bf16x8 af[4], bfr[4];
      #pragma unroll
      for (int f=0;f<4;f++){
        const int ra = wm*64 + f*16 + lo;
        const int jc = kk*4 + hi;
        af[f] = *(const bf16x8*)(Al + ra*64 + ((jc^(ra&7))*8));
        const int rb = wn*64 + f*16 + lo;
        bfr[f] = *(const bf16x8*)(Bl + rb*64 + ((jc^(rb&7))*8));
      }
      #pragma unroll
      for (int fm=0;fm<4;fm++){
        #pragma unroll
        for (int fn=0;fn<4;fn++)
          acc[fm][fn] = __builtin_amdgcn_mfma_f32_16x16x32_bf16(af[fm], bfr[fn], acc[fm][fn], 0,0,0);
      }
    }
    __syncthreads();
  }
}

// ---------------- score: ss + gamma*bivector, write S1 f32 and S1T bf16 -----------
__global__ __launch_bounds__(256) void k_score(const u16* __restrict__ qkv, const float* __restrict__ Nqp,
                                               const float* __restrict__ Nkp, const float* __restrict__ gptr,
                                               float* __restrict__ S1, u16* __restrict__ S1T){
  __shared__ __align__(16) u16 Al[128*64];
  __shared__ __align__(16) u16 Bl[128*64];
  __shared__ __align__(16) u16 Tl[128*136];
  const int wg = blockIdx.x;
  const int bid = (wg&7)*32 + (wg>>3);
  const int bh = bid>>4, ti=(bid>>2)&3, tj=bid&3;
  const int b = bh>>3, h = bh&7;
  const int i0=ti*128, j0=tj*128;
  const int t=threadIdx.x, lane=t&63, wid=t>>6;
  const int wm=wid>>1, wn=wid&1, lo=lane&15, hi=lane>>4;
  f32x4 acc[4][4];
  #pragma unroll
  for(int a=0;a<4;a++){
    #pragma unroll
    for(int c=0;c<4;c++){ acc[a][c] = (f32x4){0.f,0.f,0.f,0.f}; }
  }
  const u16* Abase = qkv + ((size_t)(b*512+i0))*24576 + h*1024;
  const u16* Bbase = qkv + ((size_t)(b*512+j0))*24576 + 8192 + h*1024;
  mm_steps(Abase, 24576, Bbase, 24576, 16, Al, Bl, acc, lane, wid);
  const float gamma = *gptr;
  const float rhd = 0.17677669529663687f; // 1/sqrt(32)
  float nkv[4];
  #pragma unroll
  for (int fn=0;fn<4;fn++){
    const int idx = bh*512 + j0 + wn*64 + fn*16 + lo;
    nkv[fn] = Nkp[idx] + Nkp[8192 + idx];
  }
  #pragma unroll
  for (int fm=0;fm<4;fm++){
    #pragma unroll
    for (int r=0;r<4;r++){
      const int iL = wm*64 + fm*16 + hi*4 + r;
      const int qidx = bh*512 + i0 + iL;
      const float nq = Nqp[qidx] + Nqp[8192 + qidx];
      #pragma unroll
      for (int fn=0;fn<4;fn++){
        const int jL = wn*64 + fn*16 + lo;
        const float ss = acc[fm][fn][r];
        const float biv = sqrtf(fmaxf(nq*nkv[fn] - ss*ss, 0.f) + 1e-6f);
        const float sc = (ss + gamma*biv)*rhd;
        S1[((size_t)bh*512 + i0 + iL)*512 + j0 + jL] = sc;
        Tl[jL*136 + iL] = f2bf(sc);
      }
    }
  }
  __syncthreads();
  const int jj = t>>1, half = t&1;
  u16* dst = S1T + ((size_t)bh*512 + (j0+jj))*512 + i0 + half*64;
  #pragma unroll
  for (int q=0;q<8;q++)
    *(uint4*)(dst + q*8) = *(const uint4*)(Tl + jj*136 + half*64 + q*8);
}

// ---------------- row softmax, wave-per-row (optionally masked) -------------------
__global__ __launch_bounds__(256) void k_softmax(const float* __restrict__ S, const int* __restrict__ mask,
                                                 u16* __restrict__ P, int masked){
  const int t = threadIdx.x, lane = t&63, wid = t>>6;
  const int row = blockIdx.x*4 + wid;   // bh*512 + i
  const int b = row>>12;
  const float* sp = S + (size_t)row*512;
  float4 a = *(const float4*)(sp + lane*4);
  float4 c = *(const float4*)(sp + 256 + lane*4);
  if (masked){
    const int* mp = mask + b*512;
    int4 ma = *(const int4*)(mp + lane*4);
    int4 mc = *(const int4*)(mp + 256 + lane*4);
    if (ma.x==0) a.x=-1e9f; if (ma.y==0) a.y=-1e9f; if (ma.z==0) a.z=-1e9f; if (ma.w==0) a.w=-1e9f;
    if (mc.x==0) c.x=-1e9f; if (mc.y==0) c.y=-1e9f; if (mc.z==0) c.z=-1e9f; if (mc.w==0) c.w=-1e9f;
  }
  float mx = fmaxf(fmaxf(fmaxf(a.x,a.y),fmaxf(a.z,a.w)), fmaxf(fmaxf(c.x,c.y),fmaxf(c.z,c.w)));
  #pragma unroll
  for (int o=1;o<64;o<<=1) mx = fmaxf(mx, __shfl_xor(mx,o));
  const float e0=__expf(a.x-mx), e1=__expf(a.y-mx), e2=__expf(a.z-mx), e3=__expf(a.w-mx);
  const float e4=__expf(c.x-mx), e5=__expf(c.y-mx), e6=__expf(c.z-mx), e7=__expf(c.w-mx);
  float sm = (e0+e1)+(e2+e3)+(e4+e5)+(e6+e7);
  #pragma unroll
  for (int o=1;o<64;o<<=1) sm += __shfl_xor(sm,o);
  const float inv = 1.f/sm;
  u16* pp = P + (size_t)row*512;
  *(uint2*)(pp + lane*4)       = make_uint2(pack2(e0*inv,e1*inv), pack2(e2*inv,e3*inv));
  *(uint2*)(pp + 256 + lane*4) = make_uint2(pack2(e4*inv,e5*inv), pack2(e6*inv,e7*inv));
}

// ---------------- triangle update: S1 += 0.1 * P1 @ S1b (in place, f32) ----------
__global__ __launch_bounds__(256) void k_tri(const u16* __restrict__ P1, const u16* __restrict__ S1T,
                                             float* __restrict__ S1){
  __shared__ __align__(16) u16 Al[128*64];
  __shared__ __align__(16) u16 Bl[128*64];
  const int wg = blockIdx.x;
  const int bid = (wg&7)*32 + (wg>>3);
  const int bh = bid>>4, ti=(bid>>2)&3, tj=bid&3;
  const int i0=ti*128, j0=tj*128;
  const int t=threadIdx.x, lane=t&63, wid=t>>6;
  const int wm=wid>>1, wn=wid&1, lo=lane&15, hi=lane>>4;
  f32x4 acc[4][4];
  #pragma unroll
  for(int a=0;a<4;a++){
    #pragma unroll
    for(int c=0;c<4;c++){ acc[a][c] = (f32x4){0.f,0.f,0.f,0.f}; }
  }
  const u16* Abase = P1  + ((size_t)bh*512 + i0)*512;
  const u16* Bbase = S1T + ((size_t)bh*512 + j0)*512;
  mm_steps(Abase, 512, Bbase, 512, 8, Al, Bl, acc, lane, wid);
  #pragma unroll
  for (int fm=0;fm<4;fm++){
    #pragma unroll
    for (int r=0;r<4;r++){
      const int iL = wm*64 + fm*16 + hi*4 + r;
      #pragma unroll
      for (int fn=0;fn<4;fn++){
        const int jL = wn*64 + fn*16 + lo;
        const size_t idx = ((size_t)bh*512 + i0 + iL)*512 + j0 + jL;
        S1[idx] = S1[idx] + 0.1f*acc[fm][fn][r];
      }
    }
  }
}

// ---------------- transpose V to VT[bh][d][s] ------------------------------------
__global__ __launch_bounds__(256) void k_tr_v(const u16* __restrict__ qkv, u16* __restrict__ VT){
  __shared__ u16 tile[128*129];
  const int bid=blockIdx.x;
  const int bh = bid>>5, dch=(bid>>2)&7, sch=bid&3;
  const int b=bh>>3, h=bh&7;
  const int d0=dch*128, s0=sch*128;
  const int t=threadIdx.x;
  {
    const int r=t>>1, half=t&1;
    const u16* src = qkv + ((size_t)(b*512+s0+r))*24576 + 16384 + h*1024 + d0 + half*64;
    #pragma unroll
    for (int q=0;q<8;q++){
      uint4 v = *(const uint4*)(src + q*8);
      u16* dp = tile + r*129 + half*64 + q*8;
      dp[0]=(u16)(v.x&0xffffu); dp[1]=(u16)(v.x>>16); dp[2]=(u16)(v.y&0xffffu); dp[3]=(u16)(v.y>>16);
      dp[4]=(u16)(v.z&0xffffu); dp[5]=(u16)(v.z>>16); dp[6]=(u16)(v.w&0xffffu); dp[7]=(u16)(v.w>>16);
    }
  }
  __syncthreads();
  {
    const int rr=t>>1, half=t&1;
    u16* dst = VT + ((size_t)bh*1024 + d0+rr)*512 + s0 + half*64;
    #pragma unroll
    for (int q=0;q<4;q++){
      u32 w[8];
      #pragma unroll
      for (int e=0;e<8;e++){
        const int s = half*64 + q*16 + e*2;
        w[e] = (u32)tile[s*129+rr] | ((u32)tile[(s+1)*129+rr]<<16);
      }
      *(uint4*)(dst + q*16)     = make_uint4(w[0],w[1],w[2],w[3]);
      *(uint4*)(dst + q*16 + 8) = make_uint4(w[4],w[5],w[6],w[7]);
    }
  }
}

// ---------------- PV: out = P2 @ V, epilogue writes mat-basis Amat2 ---------------
__global__ __launch_bounds__(256) void k_pv(const u16* __restrict__ P2, const u16* __restrict__ VT,
                                            u16* __restrict__ Am2){
  __shared__ __align__(16) u16 Al[128*64];
  __shared__ __align__(16) u16 Bl[128*64];
  __shared__ __align__(16) u16 Tl[128*136];
  const int wg = blockIdx.x;
  const int bid = (wg&7)*64 + (wg>>3);
  const int bh = bid>>5, ti=(bid>>3)&3, td=bid&7;
  const int b=bh>>3, h=bh&7;
  const int i0=ti*128, d0=td*128;
  const int t=threadIdx.x, lane=t&63, wid=t>>6;
  const int wm=wid>>1, wn=wid&1, lo=lane&15, hi=lane>>4;
  f32x4 acc[4][4];
  #pragma unroll
  for(int a=0;a<4;a++){
    #pragma unroll
    for(int c=0;c<4;c++){ acc[a][c] = (f32x4){0.f,0.f,0.f,0.f}; }
  }
  const u16* Abase = P2 + ((size_t)bh*512 + i0)*512;
  const u16* Bbase = VT + ((size_t)bh*1024 + d0)*512;
  mm_steps(Abase, 512, Bbase, 512, 8, Al, Bl, acc, lane, wid);
  #pragma unroll
  for (int fm=0;fm<4;fm++){
    #pragma unroll
    for (int r=0;r<4;r++){
      const int sL = wm*64 + fm*16 + hi*4 + r;
      #pragma unroll
      for (int fn=0;fn<4;fn++){
        const int dL = wn*64 + fn*16 + lo;
        Tl[sL*136 + dL] = f2bf(acc[fm][fn][r]);
      }
    }
  }
  __syncthreads();
  // reassemble multivectors (128 s x 4 hd) and write A-matrix rows for gemm<1>
  #pragma unroll
  for (int u=0;u<2;u++){
    const int idx = t + u*256;
    const int sL = idx>>2, hdL = idx&3;
    const u16* tp = Tl + sL*136 + hdL*32;
    float xv[32];
    #pragma unroll
    for (int q=0;q<4;q++){
      uint4 v = *(const uint4*)(tp + q*8);
      xv[q*8+0]=bf2f((u16)(v.x&0xffffu)); xv[q*8+1]=bf2f((u16)(v.x>>16));
      xv[q*8+2]=bf2f((u16)(v.y&0xffffu)); xv[q*8+3]=bf2f((u16)(v.y>>16));
      xv[q*8+4]=bf2f((u16)(v.z&0xffffu)); xv[q*8+5]=bf2f((u16)(v.z>>16));
      xv[q*8+6]=bf2f((u16)(v.w&0xffffu)); xv[q*8+7]=bf2f((u16)(v.w>>16));
    }
    float Mre[4][4], Mim[4][4];
    mv2mat(xv, Mre, Mim);
    const int e = h*32 + td*4 + hdL;
    const size_t mrow = ((size_t)(b*512 + i0 + sL))*4;
    #pragma unroll
    for (int c=0;c<4;c++){
      u32 w0 = pack2(Mre[0][c], Mre[1][c]);
      u32 w1 = pack2(Mre[2][c], Mre[3][c]);
      u32 w2 = pack2(Mim[0][c], Mim[1][c]);
      u32 w3 = pack2(Mim[2][c], Mim[3][c]);
      *(uint4*)(Am2 + (mrow + c)*2048 + e*8) = make_uint4(w0,w1,w2,w3);
    }
  }
}

extern "C" void kernel_launch(void* const* d_in, const int* in_sizes, int n_in,
                              void* d_out, int out_size, void* d_ws, size_t ws_size,
                              hipStream_t stream) {
  const float* x  = (const float*)d_in[0];
  const float* wq = (const float*)d_in[1];
  const float* wk = (const float*)d_in[2];
  const float* wv = (const float*)d_in[3];
  const float* wo = (const float*)d_in[4];
  const float* gamma = (const float*)d_in[5];
  const int*   mask  = (const int*)d_in[6];
  float* out = (float*)d_out;

  char* ws = (char*)d_ws;
  size_t off = 0;
  auto alloc = [&](size_t n){ char* p = ws + off; off += (n + 255) & ~(size_t)255; return p; };
  u16*  Am  = (u16*) alloc(16777216);   // [4096][2048] bf16 (later: P1 8MB, then Am2)
  u16*  Bfo = (u16*) alloc(33554432);   // [4][32][128][2][64][8] bf16
  u16*  qkv = (u16*) alloc(50331648);   // [1024][768][32] bf16
  float* Nqp = (float*)alloc(65536);    // [2][8192]
  float* Nkp = (float*)alloc(65536);
  float* S1 = (float*)alloc(16777216);  // [16][512][512] f32 (later: VT)
  u16*  S1T = (u16*) alloc(8388608);
  u16*  P2  = (u16*) alloc(8388608);
  u16*  P1  = (u16*)Am;                 // alias: Am dead after gemm<0>
  u16*  VT  = (u16*)S1;                 // alias: S1 dead after softmax2
  u16*  Am2 = (u16*)Am;                 // alias: P1 dead after k_tri

  k_v2m<<<1024, 256, 0, stream>>>(x, Am);
  k_w2m<<<1024, 256, 0, stream>>>(wq, wk, wv, wo, Bfo);
  k_mgemm<0><<<1536, 256, 0, stream>>>(Am, Bfo, qkv, nullptr, Nqp, Nkp);
  k_score<<<256, 256, 0, stream>>>(qkv, Nqp, Nkp, gamma, S1, S1T);
  k_softmax<<<2048, 256, 0, stream>>>(S1, mask, P1, 0);
  k_tri<<<256, 256, 0, stream>>>(P1, S1T, S1);
  k_softmax<<<2048, 256, 0, stream>>>(S1, mask, P2, 1);
  k_tr_v<<<512, 256, 0, stream>>>(qkv, VT);
  k_pv<<<512, 256, 0, stream>>>(P2, VT, Am2);
  k_mgemm<1><<<512, 256, 0, stream>>>(Am2, Bfo, nullptr, out, nullptr, nullptr);
}

// Round 17
// 263.834 us; speedup vs baseline: 1.3863x; 1.0445x over previous
//
#include <hip/hip_runtime.h>
#include <stdint.h>

typedef unsigned short u16;
typedef unsigned int u32;
typedef __attribute__((ext_vector_type(8))) __bf16 bf16x8;
typedef __attribute__((ext_vector_type(4))) float f32x4;

#define DEVINL __device__ __forceinline__

DEVINL float bf2f(u16 u){ union{u32 i; float f;} c; c.i = ((u32)u)<<16; return c.f; }
DEVINL u16 f2bf(float f){ union{float f; u32 i;} c; c.f=f; u32 u=c.i; return (u16)((u + 0x7fffu + ((u>>16)&1u))>>16); }
DEVINL u32 pack2(float a, float b){ return (u32)f2bf(a) | ((u32)f2bf(b)<<16); }

// parity of sign(e_a * e_b) in Cl(4,1) (used only for SIG_DIAG fold: sign of e_l^2)
DEVINL int sign_neg(int a, int b){
  int s = __popc((a>>1)&b) + __popc((a>>2)&b) + __popc((a>>3)&b) + __popc((a>>4)&b) + ((a&b)>>4);
  return s & 1;
}

// ---- Cl(4,1) -> M4(C) rep: blade I -> generalized permutation matrix:
// row r has single nonzero i^ph[I][r] at column col[I][r].
struct GTab { int col[32][4]; int ph[32][4]; };
constexpr GTab make_gtab(){
  GTab g{};
  int gc[5][4] = {}; int gp[5][4] = {};
  for (int r=0;r<4;r++){
    const int a=(r>>1)&1, b=r&1;
    gc[0][r]=r^2; gp[0][r]=0;                        // e0 = s1 x I
    gc[1][r]=r^2; gp[1][r]= a?1:3;                   // e1 = s2 x I
    gc[2][r]=r^1; gp[2][r]= a?2:0;                   // e2 = s3 x s1
    gc[3][r]=r^1; gp[3][r]=((a?2:0)+(b?1:3))&3;      // e3 = s3 x s2
    gc[4][r]=r;   gp[4][r]=(3+(a?2:0)+(b?2:0))&3;    // e4 = -i s3 x s3 (e4^2=-I)
  }
  for (int I=0;I<32;I++){
    for (int r=0;r<4;r++){ g.col[I][r]=r; g.ph[I][r]=0; }
    for (int bit=0;bit<5;bit++) if ((I>>bit)&1){
      for (int r=0;r<4;r++){
        const int c = g.col[I][r];
        g.ph[I][r]  = (g.ph[I][r] + gp[bit][c]) & 3;
        g.col[I][r] = gc[bit][c];
      }
    }
  }
  return g;
}
constexpr GTab GT = make_gtab();

// mv (32 reals) -> 4x4 complex matrix
DEVINL void mv2mat(const float (&x)[32], float (&Mre)[4][4], float (&Mim)[4][4]){
  #pragma unroll
  for (int r=0;r<4;r++)
    #pragma unroll
    for (int c=0;c<4;c++){ Mre[r][c]=0.f; Mim[r][c]=0.f; }
  #pragma unroll
  for (int l=0;l<32;l++){
    #pragma unroll
    for (int r=0;r<4;r++){
      constexpr const GTab& G = GT;
      const int c = G.col[l][r], p = G.ph[l][r];
      if (p==0) Mre[r][c] += x[l];
      else if (p==1) Mim[r][c] += x[l];
      else if (p==2) Mre[r][c] -= x[l];
      else Mim[r][c] -= x[l];
    }
  }
}

// v[c][r8] (r8<4: Re M[r8][c], r8>=4: Im M[r8-4][c]) -> mv
DEVINL void mat2mv(const float (&v)[4][8], float (&x)[32]){
  #pragma unroll
  for (int l=0;l<32;l++){
    float s = 0.f;
    #pragma unroll
    for (int r=0;r<4;r++){
      constexpr const GTab& G = GT;
      const int c = G.col[l][r], p = G.ph[l][r];
      if (p==0) s += v[c][r];
      else if (p==1) s += v[c][4+r];
      else if (p==2) s -= v[c][r];
      else s -= v[c][4+r];
    }
    x[l] = 0.25f*s;
  }
}

DEVINL void gload_lds16(const void* g, void* l){
  __builtin_amdgcn_global_load_lds(
    (const __attribute__((address_space(1))) void*)g,
    (__attribute__((address_space(3))) void*)l, 16, 0, 0);
}

// ---------------- x -> A-matrix: Am[(bs*4+c)][i*8+kk8] bf16 ----------------------
__global__ __launch_bounds__(256) void k_v2m(const float* __restrict__ x, u16* __restrict__ Am){
  const int bs = blockIdx.x, i = threadIdx.x;
  const float* xp = x + ((size_t)bs*256 + i)*32;
  float xv[32];
  #pragma unroll
  for (int q=0;q<8;q++){
    float4 v = *(const float4*)(xp + q*4);
    xv[q*4+0]=v.x; xv[q*4+1]=v.y; xv[q*4+2]=v.z; xv[q*4+3]=v.w;
  }
  float Mre[4][4], Mim[4][4];
  mv2mat(xv, Mre, Mim);
  #pragma unroll
  for (int c=0;c<4;c++){
    u32 w0 = pack2(Mre[0][c], Mre[1][c]);
    u32 w1 = pack2(Mre[2][c], Mre[3][c]);
    u32 w2 = pack2(Mim[0][c], Mim[1][c]);
    u32 w3 = pack2(Mim[2][c], Mim[3][c]);
    *(uint4*)(Am + ((size_t)(bs*4+c))*2048 + i*8) = make_uint4(w0,w1,w2,w3);
  }
}

// ---------------- w -> B fragment-order --------------------------------------------
__global__ __launch_bounds__(256) void k_w2m(const float* __restrict__ wq, const float* __restrict__ wk,
                                             const float* __restrict__ wv, const float* __restrict__ wo,
                                             u16* __restrict__ Bfo){
  const int bid = blockIdx.x, i = threadIdx.x;
  const int wsel = bid>>8, o = bid&255;
  const float* w = wsel==0?wq: wsel==1?wk: wsel==2?wv: wo;
  const float* wp = w + ((size_t)o*256 + i)*32;
  float wv32[32];
  #pragma unroll
  for (int q=0;q<8;q++){
    float4 v = *(const float4*)(wp + q*4);
    wv32[q*4+0]=v.x; wv32[q*4+1]=v.y; wv32[q*4+2]=v.z; wv32[q*4+3]=v.w;
  }
  float Wre[4][4], Wim[4][4];
  mv2mat(wv32, Wre, Wim);
  u16* base = Bfo + (size_t)wsel*4194304 + (size_t)(i>>3)*131072 + (o>>1)*1024
            + ((i>>2)&1)*512;
  const int lanebase = (o&1)*8 + (i&3)*16;
  #pragma unroll
  for (int r8=0;r8<8;r8++){
    float e0,e1,e2,e3,e4,e5,e6,e7;
    if (r8<4){
      e0=Wre[r8][0]; e1=Wre[r8][1]; e2=Wre[r8][2]; e3=Wre[r8][3];
      e4=-Wim[r8][0]; e5=-Wim[r8][1]; e6=-Wim[r8][2]; e7=-Wim[r8][3];
    } else {
      e0=Wim[r8-4][0]; e1=Wim[r8-4][1]; e2=Wim[r8-4][2]; e3=Wim[r8-4][3];
      e4=Wre[r8-4][0]; e5=Wre[r8-4][1]; e6=Wre[r8-4][2]; e7=Wre[r8-4][3];
    }
    *(uint4*)(base + (lanebase + r8)*8) =
      make_uint4(pack2(e0,e1), pack2(e2,e3), pack2(e4,e5), pack2(e6,e7));
  }
}

// ---- one k-phase of the matrix-basis GEMM ----------------------------------------
DEVINL void mg_phase(int kq, int cbuf, const u16* __restrict__ Wsel, const int (&boff)[4][2],
                     const u16* __restrict__ Am, int row0, int sbase, int lane,
                     u16* SM, uint4 (&B0)[4], uint4 (&B0n)[4],
                     f32x4 (&acc)[4][4], int wm, int wn, int lo, int hi){
  const u16* Wq = Wsel + (size_t)kq*131072;
  uint4 B1[4];
  #pragma unroll
  for (int fn=0; fn<4; ++fn) B1[fn] = *(const uint4*)(Wq + boff[fn][1]);
  // outstanding: A(kq)4 (oldest) + B0(kq)4 + B1(kq)4 = 12 -> retire A(kq)
  asm volatile("s_waitcnt vmcnt(8)" ::: "memory");
  __builtin_amdgcn_sched_barrier(0);
  __builtin_amdgcn_s_barrier();                // all waves' A(kq) landed; buf^1 free
  __builtin_amdgcn_sched_barrier(0);
  if (kq+1 < 32){                              // stage A(kq+1)
    #pragma unroll
    for (int cc=0;cc<4;cc++){
      const int base = sbase + cc*64;
      const int idx = base + lane;
      const int rr = idx>>3, g = idx&7;
      gload_lds16(Am + (size_t)(row0+rr)*2048 + (kq+1)*64 + ((g^(rr&7))*8),
                  SM + (cbuf^1)*8192 + base*8);
    }
  }
  const u16* Ab = SM + cbuf*8192;
  bf16x8 af0[4];
  #pragma unroll
  for (int f=0;f<4;f++){
    const int ra = wm*64 + f*16 + lo;
    af0[f] = *(const bf16x8*)(Ab + ra*64 + ((hi ^ (ra&7))*8));
  }
  if (kq+1 < 32){                              // prefetch next kk0 frags (full-phase cover)
    const u16* Wn = Wq + 131072;
    #pragma unroll
    for (int fn=0; fn<4; ++fn) B0n[fn] = *(const uint4*)(Wn + boff[fn][0]);
  }
  __builtin_amdgcn_s_setprio(1);
  #pragma unroll
  for (int fm=0;fm<4;fm++){
    #pragma unroll
    for (int fn=0;fn<4;fn++)
      acc[fm][fn] = __builtin_amdgcn_mfma_f32_16x16x32_bf16(
          af0[fm], *(const bf16x8*)&B0[fn], acc[fm][fn], 0,0,0);
  }
  __builtin_amdgcn_s_setprio(0);
  bf16x8 af1[4];
  #pragma unroll
  for (int f=0;f<4;f++){
    const int ra = wm*64 + f*16 + lo;
    af1[f] = *(const bf16x8*)(Ab + ra*64 + (((4+hi) ^ (ra&7))*8));
  }
  __builtin_amdgcn_s_setprio(1);
  #pragma unroll
  for (int fm=0;fm<4;fm++){
    #pragma unroll
    for (int fn=0;fn<4;fn++)
      acc[fm][fn] = __builtin_amdgcn_mfma_f32_16x16x32_bf16(
          af1[fm], *(const bf16x8*)&B1[fn], acc[fm][fn], 0,0,0);
  }
  __builtin_amdgcn_s_setprio(0);
}

// ---------------- matrix-basis GEMM: C = Am x Bfo, fused m2v epilogue --------------
template<int EPI>
__global__ __launch_bounds__(256) void k_mgemm(const u16* __restrict__ Am, const u16* __restrict__ Bfo,
                                               u16* __restrict__ qkv, float* __restrict__ dout,
                                               float* __restrict__ Nqp, float* __restrict__ Nkp){
  constexpr int NT = (EPI==0)?48:16;
  constexpr int NWG = 32*NT;
  __shared__ __align__(16) u16 SM[128*136];      // loop: A buf0 [0,8192), buf1 [8192,16384)
  const int wg = blockIdx.x;
  const int bid = (wg&7)*(NWG/8) + (wg>>3);      // bijective XCD chunking
  const int tn = bid>>5, tm = bid&31;            // tn-major: B panel per XCD
  const int row0 = tm*128, col0 = tn*128;
  const int sel   = (EPI==0)? (col0>>11) : 3;
  const int ncol0 = (EPI==0)? (col0&2047) : col0;
  const u16* Wsel = Bfo + (size_t)sel*4194304;
  const int t = threadIdx.x, lane = t&63, wid = t>>6;
  const int wm = wid>>1, wn = wid&1, lo = lane&15, hi = lane>>4;

  int boff[4][2];
  #pragma unroll
  for (int fn=0; fn<4; ++fn){
    const int nblk = (ncol0>>4) + wn*4 + fn;
    #pragma unroll
    for (int kk=0; kk<2; ++kk)
      boff[fn][kk] = (nblk*2+kk)*512 + lane*8;
  }

  f32x4 acc[4][4];
  #pragma unroll
  for(int a=0;a<4;a++){
    #pragma unroll
    for(int b=0;b<4;b++){ acc[a][b] = (f32x4){0.f,0.f,0.f,0.f}; }
  }

  const int sbase = (wid*4)*64;
  #pragma unroll
  for (int cc=0;cc<4;cc++){
    const int base = sbase + cc*64;
    const int idx = base + lane;
    const int rr = idx>>3, g = idx&7;
    gload_lds16(Am + (size_t)(row0+rr)*2048 + ((g^(rr&7))*8), SM + base*8);
  }
  uint4 B0a[4], B0b[4];
  #pragma unroll
  for (int fn=0; fn<4; ++fn) B0a[fn] = *(const uint4*)(Wsel + boff[fn][0]);

  #pragma unroll 1
  for (int kq2=0; kq2<16; ++kq2){
    mg_phase(2*kq2,   0, Wsel, boff, Am, row0, sbase, lane, SM, B0a, B0b, acc, wm, wn, lo, hi);
    mg_phase(2*kq2+1, 1, Wsel, boff, Am, row0, sbase, lane, SM, B0b, B0a, acc, wm, wn, lo, hi);
  }

  // ---- epilogue: dump C tile to LDS, reassemble multivectors, m2v + normalize ----
  __syncthreads();
  #pragma unroll
  for (int fm=0;fm<4;fm++){
    #pragma unroll
    for (int r=0;r<4;r++){
      const int mL = wm*64 + fm*16 + hi*4 + r;
      #pragma unroll
      for (int fn=0;fn<4;fn++){
        const int nL = wn*64 + fn*16 + lo;
        SM[mL*136 + nL] = f2bf(acc[fm][fn][r]);
      }
    }
  }
  __syncthreads();
  const int bsL = t>>3, oLp = t&7;
  const int bs = (row0>>2) + bsL;
  const int o0w = ncol0>>3;
  float nsum = 0.f;
  #pragma unroll
  for (int u=0;u<2;u++){
    const int oL = oLp + u*8;
    float v[4][8];
    #pragma unroll
    for (int c=0;c<4;c++){
      uint4 q4 = *(const uint4*)(SM + (bsL*4+c)*136 + oL*8);
      v[c][0]=bf2f((u16)(q4.x&0xffffu)); v[c][1]=bf2f((u16)(q4.x>>16));
      v[c][2]=bf2f((u16)(q4.y&0xffffu)); v[c][3]=bf2f((u16)(q4.y>>16));
      v[c][4]=bf2f((u16)(q4.z&0xffffu)); v[c][5]=bf2f((u16)(q4.z>>16));
      v[c][6]=bf2f((u16)(q4.w&0xffffu)); v[c][7]=bf2f((u16)(q4.w>>16));
    }
    float xs[32];
    mat2mv(v, xs);
    float s = 0.f;
    #pragma unroll
    for (int l=0;l<32;l++) s += xs[l]*xs[l];
    const float rs = rsqrtf(s + 1e-6f);
    if constexpr (EPI==0){
      nsum += s/(s+1e-6f);
      if (sel == 0){
        #pragma unroll
        for (int l=0;l<32;l++) xs[l] = sign_neg(l,l)? -xs[l]*rs : xs[l]*rs;
      } else {
        #pragma unroll
        for (int l=0;l<32;l++) xs[l] *= rs;
      }
      u16* dst = qkv + ((size_t)bs*768 + sel*256 + o0w + oL)*32;
      #pragma unroll
      for (int q=0;q<4;q++)
        *(uint4*)(dst + q*8) = make_uint4(pack2(xs[q*8+0],xs[q*8+1]), pack2(xs[q*8+2],xs[q*8+3]),
                                          pack2(xs[q*8+4],xs[q*8+5]), pack2(xs[q*8+6],xs[q*8+7]));
    } else {
      float* dst = dout + ((size_t)bs*256 + o0w + oL)*32;
      #pragma unroll
      for (int q=0;q<8;q++)
        *(float4*)(dst + q*4) = make_float4(xs[q*4+0]*rs, xs[q*4+1]*rs, xs[q*4+2]*rs, xs[q*4+3]*rs);
    }
  }
  if constexpr (EPI==0){
    if (sel < 2){
      nsum += __shfl_xor(nsum,1); nsum += __shfl_xor(nsum,2); nsum += __shfl_xor(nsum,4);
      if ((t&7)==0){
        const int half = (o0w>>4)&1, h = o0w>>5;
        const int b = bs>>9, s_ = bs&511;
        float* nd = (sel==0)? Nqp : Nkp;
        nd[half*8192 + (b*8+h)*512 + s_] = nsum;
      }
    }
  }
}

// ---------------- shared 128x128 MFMA tile engine, 1-barrier pipelined ------------
// SM layout (u16 idx): A0 @0, A1 @8192, B0 @16384, B1 @24576  (64 KB total)
DEVINL void mm_steps_p(const u16* Abase, int Astride, const u16* Bbase, int Bstride, int ksteps,
                       u16* SM, f32x4 (&acc)[4][4], int lane, int wid){
  const int wm = wid>>1, wn = wid&1, lo = lane&15, hi = lane>>4;
  // prologue: stage tile 0 into buf0
  #pragma unroll
  for (int c=0;c<4;c++){
    const int gb = (wid*4+c)*64;
    const int idx = gb + lane;
    const int r = idx>>3, j = idx&7;
    const int sw = ((j^(r&7))*8);
    gload_lds16(Abase + (size_t)r*Astride + sw, SM + gb*8);
    gload_lds16(Bbase + (size_t)r*Bstride + sw, SM + 16384 + gb*8);
  }
  int cbuf = 0;
  for (int s=0; s<ksteps; ++s){
    // only stage(s)'s 8 loads outstanding (issued one full phase ago -> covered)
    asm volatile("s_waitcnt vmcnt(0)" ::: "memory");
    __builtin_amdgcn_sched_barrier(0);
    __builtin_amdgcn_s_barrier();
    __builtin_amdgcn_sched_barrier(0);
    if (s+1 < ksteps){
      const int k0 = (s+1)*64;
      #pragma unroll
      for (int c=0;c<4;c++){
        const int gb = (wid*4+c)*64;
        const int idx = gb + lane;
        const int r = idx>>3, j = idx&7;
        const int sw = ((j^(r&7))*8);
        gload_lds16(Abase + (size_t)r*Astride + k0 + sw, SM + (cbuf^1)*8192 + gb*8);
        gload_lds16(Bbase + (size_t)r*Bstride + k0 + sw, SM + 16384 + (cbuf^1)*8192 + gb*8);
      }
    }
    const u16* Al = SM + cbuf*8192;
    const u16* Blc = SM + 16384 + cbuf*8192;
    #pragma unroll
    for (int kk=0; kk<2; ++kk){
      bf16x8 af[4], bfr[4];
      #pragma unroll
      for (int f=0;f<4;f++){
        const int ra = wm*64 + f*16 + lo;
        const int jc = kk*4 + hi;
        af[f] = *(const bf16x8*)(Al + ra*64 + ((jc^(ra&7))*8));
        const int rb = wn*64 + f*16 + lo;
        bfr[f] = *(const bf16x8*)(Blc + rb*64 + ((jc^(rb&7))*8));
      }
      __builtin_amdgcn_s_setprio(1);
      #pragma unroll
      for (int fm=0;fm<4;fm++){
        #pragma unroll
        for (int fn=0;fn<4;fn++)
          acc[fm][fn] = __builtin_amdgcn_mfma_f32_16x16x32_bf16(af[fm], bfr[fn], acc[fm][fn], 0,0,0);
      }
      __builtin_amdgcn_s_setprio(0);
    }
    cbuf ^= 1;
  }
}

// ---------------- score: ss + gamma*bivector, write S1 f32 and S1T bf16 -----------
__global__ __launch_bounds__(256) void k_score(const u16* __restrict__ qkv, const float* __restrict__ Nqp,
                                               const float* __restrict__ Nkp, const float* __restrict__ gptr,
                                               float* __restrict__ S1, u16* __restrict__ S1T){
  __shared__ __align__(16) u16 SM[32768];
  u16* Tl = SM;                                   // aliased post-loop (barrier-protected)
  const int wg = blockIdx.x;
  const int bid = (wg&7)*32 + (wg>>3);
  const int bh = bid>>4, ti=(bid>>2)&3, tj=bid&3;
  const int b = bh>>3, h = bh&7;
  const int i0=ti*128, j0=tj*128;
  const int t=threadIdx.x, lane=t&63, wid=t>>6;
  const int wm=wid>>1, wn=wid&1, lo=lane&15, hi=lane>>4;
  f32x4 acc[4][4];
  #pragma unroll
  for(int a=0;a<4;a++){
    #pragma unroll
    for(int c=0;c<4;c++){ acc[a][c] = (f32x4){0.f,0.f,0.f,0.f}; }
  }
  const u16* Abase = qkv + ((size_t)(b*512+i0))*24576 + h*1024;
  const u16* Bbase = qkv + ((size_t)(b*512+j0))*24576 + 8192 + h*1024;
  mm_steps_p(Abase, 24576, Bbase, 24576, 16, SM, acc, lane, wid);
  __syncthreads();                                // all waves done with SM buffers
  const float gamma = *gptr;
  const float rhd = 0.17677669529663687f; // 1/sqrt(32)
  float nkv[4];
  #pragma unroll
  for (int fn=0;fn<4;fn++){
    const int idx = bh*512 + j0 + wn*64 + fn*16 + lo;
    nkv[fn] = Nkp[idx] + Nkp[8192 + idx];
  }
  #pragma unroll
  for (int fm=0;fm<4;fm++){
    #pragma unroll
    for (int r=0;r<4;r++){
      const int iL = wm*64 + fm*16 + hi*4 + r;
      const int qidx = bh*512 + i0 + iL;
      const float nq = Nqp[qidx] + Nqp[8192 + qidx];
      #pragma unroll
      for (int fn=0;fn<4;fn++){
        const int jL = wn*64 + fn*16 + lo;
        const float ss = acc[fm][fn][r];
        const float biv = sqrtf(fmaxf(nq*nkv[fn] - ss*ss, 0.f) + 1e-6f);
        const float sc = (ss + gamma*biv)*rhd;
        S1[((size_t)bh*512 + i0 + iL)*512 + j0 + jL] = sc;
        Tl[jL*136 + iL] = f2bf(sc);
      }
    }
  }
  __syncthreads();
  const int jj = t>>1, half = t&1;
  u16* dst = S1T + ((size_t)bh*512 + (j0+jj))*512 + i0 + half*64;
  #pragma unroll
  for (int q=0;q<8;q++)
    *(uint4*)(dst + q*8) = *(const uint4*)(Tl + jj*136 + half*64 + q*8);
}

// ---------------- row softmax, wave-per-row (optionally masked) -------------------
__global__ __launch_bounds__(256) void k_softmax(const float* __restrict__ S, const int* __restrict__ mask,
                                                 u16* __restrict__ P, int masked){
  const int t = threadIdx.x, lane = t&63, wid = t>>6;
  const int row = blockIdx.x*4 + wid;   // bh*512 + i
  const int b = row>>12;
  const float* sp = S + (size_t)row*512;
  float4 a = *(const float4*)(sp + lane*4);
  float4 c = *(const float4*)(sp + 256 + lane*4);
  if (masked){
    const int* mp = mask + b*512;
    int4 ma = *(const int4*)(mp + lane*4);
    int4 mc = *(const int4*)(mp + 256 + lane*4);
    if (ma.x==0) a.x=-1e9f; if (ma.y==0) a.y=-1e9f; if (ma.z==0) a.z=-1e9f; if (ma.w==0) a.w=-1e9f;
    if (mc.x==0) c.x=-1e9f; if (mc.y==0) c.y=-1e9f; if (mc.z==0) c.z=-1e9f; if (mc.w==0) c.w=-1e9f;
  }
  float mx = fmaxf(fmaxf(fmaxf(a.x,a.y),fmaxf(a.z,a.w)), fmaxf(fmaxf(c.x,c.y),fmaxf(c.z,c.w)));
  #pragma unroll
  for (int o=1;o<64;o<<=1) mx = fmaxf(mx, __shfl_xor(mx,o));
  const float e0=__expf(a.x-mx), e1=__expf(a.y-mx), e2=__expf(a.z-mx), e3=__expf(a.w-mx);
  const float e4=__expf(c.x-mx), e5=__expf(c.y-mx), e6=__expf(c.z-mx), e7=__expf(c.w-mx);
  float sm = (e0+e1)+(e2+e3)+(e4+e5)+(e6+e7);
  #pragma unroll
  for (int o=1;o<64;o<<=1) sm += __shfl_xor(sm,o);
  const float inv = 1.f/sm;
  u16* pp = P + (size_t)row*512;
  *(uint2*)(pp + lane*4)       = make_uint2(pack2(e0*inv,e1*inv), pack2(e2*inv,e3*inv));
  *(uint2*)(pp + 256 + lane*4) = make_uint2(pack2(e4*inv,e5*inv), pack2(e6*inv,e7*inv));
}

// ---------------- triangle update: S1 += 0.1 * P1 @ S1b (in place, f32) ----------
__global__ __launch_bounds__(256) void k_tri(const u16* __restrict__ P1, const u16* __restrict__ S1T,
                                             float* __restrict__ S1){
  __shared__ __align__(16) u16 SM[32768];
  const int wg = blockIdx.x;
  const int bid = (wg&7)*32 + (wg>>3);
  const int bh = bid>>4, ti=(bid>>2)&3, tj=bid&3;
  const int i0=ti*128, j0=tj*128;
  const int t=threadIdx.x, lane=t&63, wid=t>>6;
  const int wm=wid>>1, wn=wid&1, lo=lane&15, hi=lane>>4;
  f32x4 acc[4][4];
  #pragma unroll
  for(int a=0;a<4;a++){
    #pragma unroll
    for(int c=0;c<4;c++){ acc[a][c] = (f32x4){0.f,0.f,0.f,0.f}; }
  }
  const u16* Abase = P1  + ((size_t)bh*512 + i0)*512;
  const u16* Bbase = S1T + ((size_t)bh*512 + j0)*512;
  mm_steps_p(Abase, 512, Bbase, 512, 8, SM, acc, lane, wid);
  #pragma unroll
  for (int fm=0;fm<4;fm++){
    #pragma unroll
    for (int r=0;r<4;r++){
      const int iL = wm*64 + fm*16 + hi*4 + r;
      #pragma unroll
      for (int fn=0;fn<4;fn++){
        const int jL = wn*64 + fn*16 + lo;
        const size_t idx = ((size_t)bh*512 + i0 + iL)*512 + j0 + jL;
        S1[idx] = S1[idx] + 0.1f*acc[fm][fn][r];
      }
    }
  }
}

// ---------------- transpose V to VT[bh][d][s] ------------------------------------
__global__ __launch_bounds__(256) void k_tr_v(const u16* __restrict__ qkv, u16* __restrict__ VT){
  __shared__ u16 tile[128*129];
  const int bid=blockIdx.x;
  const int bh = bid>>5, dch=(bid>>2)&7, sch=bid&3;
  const int b=bh>>3, h=bh&7;
  const int d0=dch*128, s0=sch*128;
  const int t=threadIdx.x;
  {
    const int r=t>>1, half=t&1;
    const u16* src = qkv + ((size_t)(b*512+s0+r))*24576 + 16384 + h*1024 + d0 + half*64;
    #pragma unroll
    for (int q=0;q<8;q++){
      uint4 v = *(const uint4*)(src + q*8);
      u16* dp = tile + r*129 + half*64 + q*8;
      dp[0]=(u16)(v.x&0xffffu); dp[1]=(u16)(v.x>>16); dp[2]=(u16)(v.y&0xffffu); dp[3]=(u16)(v.y>>16);
      dp[4]=(u16)(v.z&0xffffu); dp[5]=(u16)(v.z>>16); dp[6]=(u16)(v.w&0xffffu); dp[7]=(u16)(v.w>>16);
    }
  }
  __syncthreads();
  {
    const int rr=t>>1, half=t&1;
    u16* dst = VT + ((size_t)bh*1024 + d0+rr)*512 + s0 + half*64;
    #pragma unroll
    for (int q=0;q<4;q++){
      u32 w[8];
      #pragma unroll
      for (int e=0;e<8;e++){
        const int s = half*64 + q*16 + e*2;
        w[e] = (u32)tile[s*129+rr] | ((u32)tile[(s+1)*129+rr]<<16);
      }
      *(uint4*)(dst + q*16)     = make_uint4(w[0],w[1],w[2],w[3]);
      *(uint4*)(dst + q*16 + 8) = make_uint4(w[4],w[5],w[6],w[7]);
    }
  }
}

// ---------------- PV: out = P2 @ V, epilogue writes mat-basis Amat2 ---------------
__global__ __launch_bounds__(256) void k_pv(const u16* __restrict__ P2, const u16* __restrict__ VT,
                                            u16* __restrict__ Am2){
  __shared__ __align__(16) u16 SM[32768];
  u16* Tl = SM;                                   // aliased post-loop (barrier-protected)
  const int wg = blockIdx.x;
  const int bid = (wg&7)*64 + (wg>>3);
  const int bh = bid>>5, ti=(bid>>3)&3, td=bid&7;
  const int b=bh>>3, h=bh&7;
  const int i0=ti*128, d0=td*128;
  const int t=threadIdx.x, lane=t&63, wid=t>>6;
  const int wm=wid>>1, wn=wid&1, lo=lane&15, hi=lane>>4;
  f32x4 acc[4][4];
  #pragma unroll
  for(int a=0;a<4;a++){
    #pragma unroll
    for(int c=0;c<4;c++){ acc[a][c] = (f32x4){0.f,0.f,0.f,0.f}; }
  }
  const u16* Abase = P2 + ((size_t)bh*512 + i0)*512;
  const u16* Bbase = VT + ((size_t)bh*1024 + d0)*512;
  mm_steps_p(Abase, 512, Bbase, 512, 8, SM, acc, lane, wid);
  __syncthreads();                                // all waves done with SM buffers
  #pragma unroll
  for (int fm=0;fm<4;fm++){
    #pragma unroll
    for (int r=0;r<4;r++){
      const int sL = wm*64 + fm*16 + hi*4 + r;
      #pragma unroll
      for (int fn=0;fn<4;fn++){
        const int dL = wn*64 + fn*16 + lo;
        Tl[sL*136 + dL] = f2bf(acc[fm][fn][r]);
      }
    }
  }
  __syncthreads();
  // reassemble multivectors (128 s x 4 hd) and write A-matrix rows for gemm<1>
  #pragma unroll
  for (int u=0;u<2;u++){
    const int idx = t + u*256;
    const int sL = idx>>2, hdL = idx&3;
    const u16* tp = Tl + sL*136 + hdL*32;
    float xv[32];
    #pragma unroll
    for (int q=0;q<4;q++){
      uint4 v = *(const uint4*)(tp + q*8);
      xv[q*8+0]=bf2f((u16)(v.x&0xffffu)); xv[q*8+1]=bf2f((u16)(v.x>>16));
      xv[q*8+2]=bf2f((u16)(v.y&0xffffu)); xv[q*8+3]=bf2f((u16)(v.y>>16));
      xv[q*8+4]=bf2f((u16)(v.z&0xffffu)); xv[q*8+5]=bf2f((u16)(v.z>>16));
      xv[q*8+6]=bf2f((u16)(v.w&0xffffu)); xv[q*8+7]=bf2f((u16)(v.w>>16));
    }
    float Mre[4][4], Mim[4][4];
    mv2mat(xv, Mre, Mim);
    const int e = h*32 + td*4 + hdL;
    const size_t mrow = ((size_t)(b*512 + i0 + sL))*4;
    #pragma unroll
    for (int c=0;c<4;c++){
      u32 w0 = pack2(Mre[0][c], Mre[1][c]);
      u32 w1 = pack2(Mre[2][c], Mre[3][c]);
      u32 w2 = pack2(Mim[0][c], Mim[1][c]);
      u32 w3 = pack2(Mim[2][c], Mim[3][c]);
      *(uint4*)(Am2 + (mrow + c)*2048 + e*8) = make_uint4(w0,w1,w2,w3);
    }
  }
}

extern "C" void kernel_launch(void* const* d_in, const int* in_sizes, int n_in,
                              void* d_out, int out_size, void* d_ws, size_t ws_size,
                              hipStream_t stream) {
  const float* x  = (const float*)d_in[0];
  const float* wq = (const float*)d_in[1];
  const float* wk = (const float*)d_in[2];
  const float* wv = (const float*)d_in[3];
  const float* wo = (const float*)d_in[4];
  const float* gamma = (const float*)d_in[5];
  const int*   mask  = (const int*)d_in[6];
  float* out = (float*)d_out;

  char* ws = (char*)d_ws;
  size_t off = 0;
  auto alloc = [&](size_t n){ char* p = ws + off; off += (n + 255) & ~(size_t)255; return p; };
  u16*  Am  = (u16*) alloc(16777216);   // [4096][2048] bf16 (later: P1 8MB, then Am2)
  u16*  Bfo = (u16*) alloc(33554432);   // [4][32][128][2][64][8] bf16
  u16*  qkv = (u16*) alloc(50331648);   // [1024][768][32] bf16
  float* Nqp = (float*)alloc(65536);    // [2][8192]
  float* Nkp = (float*)alloc(65536);
  float* S1 = (float*)alloc(16777216);  // [16][512][512] f32 (later: VT)
  u16*  S1T = (u16*) alloc(8388608);
  u16*  P2  = (u16*) alloc(8388608);
  u16*  P1  = (u16*)Am;                 // alias: Am dead after gemm<0>
  u16*  VT  = (u16*)S1;                 // alias: S1 dead after softmax2
  u16*  Am2 = (u16*)Am;                 // alias: P1 dead after k_tri

  k_v2m<<<1024, 256, 0, stream>>>(x, Am);
  k_w2m<<<1024, 256, 0, stream>>>(wq, wk, wv, wo, Bfo);
  k_mgemm<0><<<1536, 256, 0, stream>>>(Am, Bfo, qkv, nullptr, Nqp, Nkp);
  k_score<<<256, 256, 0, stream>>>(qkv, Nqp, Nkp, gamma, S1, S1T);
  k_softmax<<<2048, 256, 0, stream>>>(S1, mask, P1, 0);
  k_tri<<<256, 256, 0, stream>>>(P1, S1T, S1);
  k_softmax<<<2048, 256, 0, stream>>>(S1, mask, P2, 1);
  k_tr_v<<<512, 256, 0, stream>>>(qkv, VT);
  k_pv<<<512, 256, 0, stream>>>(P2, VT, Am2);
  k_mgemm<1><<<512, 256, 0, stream>>>(Am2, Bfo, nullptr, out, nullptr, nullptr);
}